// Round 1
// baseline (804.172 us; speedup 1.0000x reference)
//
#include <hip/hip_runtime.h>
#include <hip/hip_bf16.h>

#define N_NODES 50000
#define N_EDGES 800000
#define DIM_IN  384
#define DIM_H   256

typedef __bf16 bf16x8 __attribute__((ext_vector_type(8)));
typedef float  f32x4  __attribute__((ext_vector_type(4)));

static __device__ __forceinline__ ushort f2bf(float f) {
  uint u = __float_as_uint(f);
  u += 0x7fffu + ((u >> 16) & 1u);
  return (ushort)(u >> 16);
}
static __device__ __forceinline__ float bf_lo(uint u) { return __uint_as_float(u << 16); }
static __device__ __forceinline__ float bf_hi(uint u) { return __uint_as_float(u & 0xffff0000u); }

// ---------------- h0 = log1p(x), f32 -> bf16 ----------------
__global__ void log1p_kernel(const float* __restrict__ x, ushort* __restrict__ h, int n4) {
  int i = blockIdx.x * 256 + threadIdx.x;
  if (i >= n4) return;
  float4 v = reinterpret_cast<const float4*>(x)[i];
  ushort4 o;
  o.x = f2bf(log1pf(v.x));
  o.y = f2bf(log1pf(v.y));
  o.z = f2bf(log1pf(v.z));
  o.w = f2bf(log1pf(v.w));
  reinterpret_cast<ushort4*>(h)[i] = o;
}

// ---------------- CSR build ----------------
__global__ void hist_kernel(const int* __restrict__ dst, int* __restrict__ deg, int e) {
  int i = blockIdx.x * 256 + threadIdx.x;
  if (i < e) atomicAdd(&deg[dst[i]], 1);
}

__global__ void scan_kernel(const int* __restrict__ deg, int* __restrict__ rowptr,
                            int* __restrict__ cursor, int n) {
  __shared__ int buf[1024];
  __shared__ int s_carry;
  int t = threadIdx.x;
  if (t == 0) s_carry = 0;
  __syncthreads();
  for (int base = 0; base < n; base += 1024) {
    int v = (base + t < n) ? deg[base + t] : 0;
    buf[t] = v;
    __syncthreads();
    int x = v;
    for (int off = 1; off < 1024; off <<= 1) {
      int y = (t >= off) ? buf[t - off] : 0;
      __syncthreads();
      x += y;
      buf[t] = x;
      __syncthreads();
    }
    int excl = x - v;
    int c = s_carry;
    if (base + t < n) { rowptr[base + t] = c + excl; cursor[base + t] = c + excl; }
    __syncthreads();
    if (t == 1023) s_carry = c + x;
    __syncthreads();
  }
}

__global__ void fill_kernel(const int* __restrict__ src, const int* __restrict__ dst,
                            int* __restrict__ cursor, int* __restrict__ csr, int e) {
  int i = blockIdx.x * 256 + threadIdx.x;
  if (i >= e) return;
  int d = dst[i];
  int p = atomicAdd(&cursor[d], 1);
  csr[p] = src[i];
}

// ---------------- weight prepack: W[k][j] f32 -> MFMA B-frag layout bf16 ----------------
// packed[((kc*256 + j)*4 + kg)*8 + e] = bf16(W[(kc*32 + kg*8 + e)*256 + j])
__global__ void pack_w_kernel(const float* __restrict__ W, ushort* __restrict__ out, int K) {
  int idx = blockIdx.x * 256 + threadIdx.x;
  if (idx >= K * 256) return;
  int k = idx >> 8, j = idx & 255;
  int kc = k >> 5, kg = (k >> 3) & 3, e = k & 7;
  out[(((kc << 8) + j) * 4 + kg) * 8 + e] = f2bf(W[idx]);
}

// ---------------- mean aggregation: one wave per dst node ----------------
template <int K>
__global__ __launch_bounds__(256) void agg_kernel(const ushort* __restrict__ h,
                                                  const int* __restrict__ rowptr,
                                                  const int* __restrict__ deg,
                                                  const int* __restrict__ csr,
                                                  ushort* __restrict__ out) {
  int node = blockIdx.x * 4 + (threadIdx.x >> 6);
  if (node >= N_NODES) return;
  int lane = threadIdx.x & 63;
  constexpr int CPL = K / 64;   // bf16 per lane (4 or 6)
  constexpr int CW  = CPL / 2;  // dwords per lane
  int start = rowptr[node];
  int d = deg[node];
  float acc[CPL];
#pragma unroll
  for (int i = 0; i < CPL; ++i) acc[i] = 0.0f;
  int baseoff = lane * CPL;
  for (int e = 0; e < d; ++e) {
    int s = csr[start + e];
    const uint* p = reinterpret_cast<const uint*>(h + (size_t)s * K + baseoff);
#pragma unroll
    for (int w = 0; w < CW; ++w) {
      uint u = p[w];
      acc[2 * w]     += bf_lo(u);
      acc[2 * w + 1] += bf_hi(u);
    }
  }
  float inv = 1.0f / fmaxf((float)d, 1.0f);
  uint* op = reinterpret_cast<uint*>(out + (size_t)node * K + baseoff);
#pragma unroll
  for (int w = 0; w < CW; ++w) {
    uint lo = f2bf(acc[2 * w] * inv);
    uint hi = f2bf(acc[2 * w + 1] * inv);
    op[w] = lo | (hi << 16);
  }
}

// ---------------- fused SAGE GEMM: out = A@Ws + G@Wn + b (+relu+l2norm) ----------------
// wave tile: 16 rows x 256 cols, 16 MFMA frags of 16x16, K-loop in steps of 32
template <int K, bool LAST>
__global__ __launch_bounds__(256) void gemm_kernel(const ushort* __restrict__ A,
                                                   const ushort* __restrict__ G,
                                                   const ushort* __restrict__ Bs,
                                                   const ushort* __restrict__ Bn,
                                                   const float* __restrict__ bias,
                                                   void* __restrict__ outv) {
  const int tile = blockIdx.x * 4 + (threadIdx.x >> 6);
  if (tile >= N_NODES / 16) return;
  const int lane = threadIdx.x & 63;
  const int lj = lane & 15, lg = lane >> 4;
  const int r0 = tile * 16;

  const ushort* ap = A + (size_t)(r0 + lj) * K + lg * 8;
  const ushort* gp = G + (size_t)(r0 + lj) * K + lg * 8;
  const ushort* bsp = Bs + lj * 32 + lg * 8;
  const ushort* bnp = Bn + lj * 32 + lg * 8;

  f32x4 acc[16];
#pragma unroll
  for (int f = 0; f < 16; ++f) acc[f] = (f32x4){0.f, 0.f, 0.f, 0.f};

  for (int kc = 0; kc < K / 32; ++kc) {
    bf16x8 a_s = *reinterpret_cast<const bf16x8*>(ap + kc * 32);
    bf16x8 a_n = *reinterpret_cast<const bf16x8*>(gp + kc * 32);
    const ushort* bs = bsp + kc * 8192;
    const ushort* bn = bnp + kc * 8192;
#pragma unroll
    for (int f = 0; f < 16; ++f) {
      bf16x8 b1 = *reinterpret_cast<const bf16x8*>(bs + f * 512);
      acc[f] = __builtin_amdgcn_mfma_f32_16x16x32_bf16(a_s, b1, acc[f], 0, 0, 0);
      bf16x8 b2 = *reinterpret_cast<const bf16x8*>(bn + f * 512);
      acc[f] = __builtin_amdgcn_mfma_f32_16x16x32_bf16(a_n, b2, acc[f], 0, 0, 0);
    }
  }

  float bv[16];
#pragma unroll
  for (int f = 0; f < 16; ++f) bv[f] = bias[f * 16 + lj];

  if (LAST) {
    float* out = reinterpret_cast<float*>(outv);
#pragma unroll
    for (int f = 0; f < 16; ++f)
#pragma unroll
      for (int e = 0; e < 4; ++e)
        out[(size_t)(r0 + lg * 4 + e) * 256 + f * 16 + lj] = acc[f][e] + bv[f];
  } else {
    ushort* out = reinterpret_cast<ushort*>(outv);
    float s[4] = {0.f, 0.f, 0.f, 0.f};
#pragma unroll
    for (int f = 0; f < 16; ++f)
#pragma unroll
      for (int e = 0; e < 4; ++e) {
        float v = acc[f][e] + bv[f];
        v = fmaxf(v, 0.0f);
        acc[f][e] = v;
        s[e] += v * v;
      }
#pragma unroll
    for (int e = 0; e < 4; ++e) {
      float t = s[e];
      t += __shfl_xor(t, 1);
      t += __shfl_xor(t, 2);
      t += __shfl_xor(t, 4);
      t += __shfl_xor(t, 8);
      s[e] = 1.0f / fmaxf(sqrtf(t), 1e-12f);
    }
#pragma unroll
    for (int f = 0; f < 16; ++f)
#pragma unroll
      for (int e = 0; e < 4; ++e)
        out[(size_t)(r0 + lg * 4 + e) * 256 + f * 16 + lj] = f2bf(acc[f][e] * s[e]);
  }
}

// ---------------- launch ----------------
extern "C" void kernel_launch(void* const* d_in, const int* in_sizes, int n_in,
                              void* d_out, int out_size, void* d_ws, size_t ws_size,
                              hipStream_t stream) {
  const float* x   = (const float*)d_in[0];
  const int*   src = (const int*)d_in[1];
  const int*   dst = (const int*)d_in[2];
  const float* Ws0 = (const float*)d_in[3];
  const float* Wn0 = (const float*)d_in[4];
  const float* b0  = (const float*)d_in[5];
  const float* Ws1 = (const float*)d_in[6];
  const float* Wn1 = (const float*)d_in[7];
  const float* b1  = (const float*)d_in[8];
  const float* Ws2 = (const float*)d_in[9];
  const float* Wn2 = (const float*)d_in[10];
  const float* b2  = (const float*)d_in[11];

  // workspace carve (256B aligned)
  uintptr_t p = ((uintptr_t)d_ws + 255) & ~(uintptr_t)255;
  auto carve = [&](size_t bytes) {
    void* r = (void*)p;
    p += (bytes + 255) & ~(size_t)255;
    return r;
  };
  ushort* h0   = (ushort*)carve((size_t)N_NODES * DIM_IN * 2);
  ushort* agg  = (ushort*)carve((size_t)N_NODES * DIM_IN * 2);
  ushort* h1   = (ushort*)carve((size_t)N_NODES * DIM_H * 2);
  ushort* h2   = (ushort*)carve((size_t)N_NODES * DIM_H * 2);
  ushort* Ws0p = (ushort*)carve((size_t)DIM_IN * 256 * 2);
  ushort* Wn0p = (ushort*)carve((size_t)DIM_IN * 256 * 2);
  ushort* Ws1p = (ushort*)carve((size_t)DIM_H * 256 * 2);
  ushort* Wn1p = (ushort*)carve((size_t)DIM_H * 256 * 2);
  ushort* Ws2p = (ushort*)carve((size_t)DIM_H * 256 * 2);
  ushort* Wn2p = (ushort*)carve((size_t)DIM_H * 256 * 2);
  int* deg    = (int*)carve((size_t)N_NODES * 4);
  int* rowptr = (int*)carve((size_t)N_NODES * 4);
  int* cursor = (int*)carve((size_t)N_NODES * 4);
  int* csr    = (int*)carve((size_t)N_EDGES * 4);

  hipMemsetAsync(deg, 0, (size_t)N_NODES * 4, stream);

  // h0 = log1p(x) -> bf16
  {
    int n4 = N_NODES * DIM_IN / 4;
    log1p_kernel<<<(n4 + 255) / 256, 256, 0, stream>>>(x, h0, n4);
  }
  // CSR
  hist_kernel<<<(N_EDGES + 255) / 256, 256, 0, stream>>>(dst, deg, N_EDGES);
  scan_kernel<<<1, 1024, 0, stream>>>(deg, rowptr, cursor, N_NODES);
  fill_kernel<<<(N_EDGES + 255) / 256, 256, 0, stream>>>(src, dst, cursor, csr, N_EDGES);
  // weight prepack
  pack_w_kernel<<<(DIM_IN * 256 + 255) / 256, 256, 0, stream>>>(Ws0, Ws0p, DIM_IN);
  pack_w_kernel<<<(DIM_IN * 256 + 255) / 256, 256, 0, stream>>>(Wn0, Wn0p, DIM_IN);
  pack_w_kernel<<<(DIM_H * 256 + 255) / 256, 256, 0, stream>>>(Ws1, Ws1p, DIM_H);
  pack_w_kernel<<<(DIM_H * 256 + 255) / 256, 256, 0, stream>>>(Wn1, Wn1p, DIM_H);
  pack_w_kernel<<<(DIM_H * 256 + 255) / 256, 256, 0, stream>>>(Ws2, Ws2p, DIM_H);
  pack_w_kernel<<<(DIM_H * 256 + 255) / 256, 256, 0, stream>>>(Wn2, Wn2p, DIM_H);

  const int aggBlocks  = (N_NODES + 3) / 4;
  const int gemmBlocks = (N_NODES / 16 + 3) / 4;

  // layer 0: 384 -> 256, relu + l2norm
  agg_kernel<DIM_IN><<<aggBlocks, 256, 0, stream>>>(h0, rowptr, deg, csr, agg);
  gemm_kernel<DIM_IN, false><<<gemmBlocks, 256, 0, stream>>>(h0, agg, Ws0p, Wn0p, b0, h1);
  // layer 1: 256 -> 256, relu + l2norm
  agg_kernel<DIM_H><<<aggBlocks, 256, 0, stream>>>(h1, rowptr, deg, csr, agg);
  gemm_kernel<DIM_H, false><<<gemmBlocks, 256, 0, stream>>>(h1, agg, Ws1p, Wn1p, b1, h2);
  // layer 2: 256 -> 256, plain
  agg_kernel<DIM_H><<<aggBlocks, 256, 0, stream>>>(h2, rowptr, deg, csr, agg);
  gemm_kernel<DIM_H, true><<<gemmBlocks, 256, 0, stream>>>(h2, agg, Ws2p, Wn2p, b2, d_out);
}

// Round 2
// 621.441 us; speedup vs baseline: 1.2940x; 1.2940x over previous
//
#include <hip/hip_runtime.h>
#include <hip/hip_bf16.h>

#define N_NODES 50000
#define N_EDGES 800000
#define DIM_IN  384
#define DIM_H   256

typedef __bf16 bf16x8 __attribute__((ext_vector_type(8)));
typedef float  f32x4  __attribute__((ext_vector_type(4)));

static __device__ __forceinline__ ushort f2bf(float f) {
  uint u = __float_as_uint(f);
  u += 0x7fffu + ((u >> 16) & 1u);
  return (ushort)(u >> 16);
}
static __device__ __forceinline__ float bf_lo(uint u) { return __uint_as_float(u << 16); }
static __device__ __forceinline__ float bf_hi(uint u) { return __uint_as_float(u & 0xffff0000u); }

// ---------------- h0 = log1p(x), f32 -> bf16 ----------------
__global__ void log1p_kernel(const float* __restrict__ x, ushort* __restrict__ h, int n4) {
  int i = blockIdx.x * 256 + threadIdx.x;
  if (i >= n4) return;
  float4 v = reinterpret_cast<const float4*>(x)[i];
  ushort4 o;
  o.x = f2bf(log1pf(v.x));
  o.y = f2bf(log1pf(v.y));
  o.z = f2bf(log1pf(v.z));
  o.w = f2bf(log1pf(v.w));
  reinterpret_cast<ushort4*>(h)[i] = o;
}

// ---------------- CSR build ----------------
__global__ void hist_kernel(const int* __restrict__ dst, int* __restrict__ deg, int e) {
  int i = blockIdx.x * 256 + threadIdx.x;
  if (i < e) atomicAdd(&deg[dst[i]], 1);
}

__global__ void scan_kernel(const int* __restrict__ deg, int* __restrict__ rowptr,
                            int* __restrict__ cursor, int n) {
  __shared__ int buf[1024];
  __shared__ int s_carry;
  int t = threadIdx.x;
  if (t == 0) s_carry = 0;
  __syncthreads();
  for (int base = 0; base < n; base += 1024) {
    int v = (base + t < n) ? deg[base + t] : 0;
    buf[t] = v;
    __syncthreads();
    int x = v;
    for (int off = 1; off < 1024; off <<= 1) {
      int y = (t >= off) ? buf[t - off] : 0;
      __syncthreads();
      x += y;
      buf[t] = x;
      __syncthreads();
    }
    int excl = x - v;
    int c = s_carry;
    if (base + t < n) { rowptr[base + t] = c + excl; cursor[base + t] = c + excl; }
    __syncthreads();
    if (t == 1023) s_carry = c + x;
    __syncthreads();
  }
}

__global__ void fill_kernel(const int* __restrict__ src, const int* __restrict__ dst,
                            int* __restrict__ cursor, int* __restrict__ csr, int e) {
  int i = blockIdx.x * 256 + threadIdx.x;
  if (i >= e) return;
  int d = dst[i];
  int p = atomicAdd(&cursor[d], 1);
  csr[p] = src[i];
}

// ---------------- weight prepack: W[k][j] f32 -> MFMA B-frag layout bf16 ----------------
// packed[(kc*256 + j)*32 + kg*8 + e] = bf16(W[(kc*32 + kg*8 + e)*256 + j])
__global__ void pack_w_kernel(const float* __restrict__ W, ushort* __restrict__ out, int K) {
  int idx = blockIdx.x * 256 + threadIdx.x;
  if (idx >= K * 256) return;
  int k = idx >> 8, j = idx & 255;
  int kc = k >> 5, kg = (k >> 3) & 3, e = k & 7;
  out[(((kc << 8) + j) * 4 + kg) * 8 + e] = f2bf(W[idx]);
}

// ---------------- mean aggregation: one wave per dst node, 4-edge ILP ----------------
template <int K>
__global__ __launch_bounds__(256) void agg_kernel(const ushort* __restrict__ h,
                                                  const int* __restrict__ rowptr,
                                                  const int* __restrict__ deg,
                                                  const int* __restrict__ csr,
                                                  ushort* __restrict__ out) {
  int node = blockIdx.x * 4 + (threadIdx.x >> 6);
  if (node >= N_NODES) return;
  int lane = threadIdx.x & 63;
  constexpr int CPL = K / 64;   // bf16 per lane (4 or 6)
  constexpr int CW  = CPL / 2;  // dwords per lane
  int start = rowptr[node];
  int d = deg[node];
  float acc[CPL];
#pragma unroll
  for (int i = 0; i < CPL; ++i) acc[i] = 0.0f;
  int baseoff = lane * CPL;

  int e = 0;
  for (; e + 4 <= d; e += 4) {
    int s0 = csr[start + e];
    int s1 = csr[start + e + 1];
    int s2 = csr[start + e + 2];
    int s3 = csr[start + e + 3];
    const uint* p0 = reinterpret_cast<const uint*>(h + (size_t)s0 * K + baseoff);
    const uint* p1 = reinterpret_cast<const uint*>(h + (size_t)s1 * K + baseoff);
    const uint* p2 = reinterpret_cast<const uint*>(h + (size_t)s2 * K + baseoff);
    const uint* p3 = reinterpret_cast<const uint*>(h + (size_t)s3 * K + baseoff);
    uint u0[CW], u1[CW], u2[CW], u3[CW];
#pragma unroll
    for (int w = 0; w < CW; ++w) u0[w] = p0[w];
#pragma unroll
    for (int w = 0; w < CW; ++w) u1[w] = p1[w];
#pragma unroll
    for (int w = 0; w < CW; ++w) u2[w] = p2[w];
#pragma unroll
    for (int w = 0; w < CW; ++w) u3[w] = p3[w];
#pragma unroll
    for (int w = 0; w < CW; ++w) {
      acc[2 * w]     += bf_lo(u0[w]) + bf_lo(u1[w]) + bf_lo(u2[w]) + bf_lo(u3[w]);
      acc[2 * w + 1] += bf_hi(u0[w]) + bf_hi(u1[w]) + bf_hi(u2[w]) + bf_hi(u3[w]);
    }
  }
  for (; e < d; ++e) {
    int s = csr[start + e];
    const uint* p = reinterpret_cast<const uint*>(h + (size_t)s * K + baseoff);
#pragma unroll
    for (int w = 0; w < CW; ++w) {
      uint u = p[w];
      acc[2 * w]     += bf_lo(u);
      acc[2 * w + 1] += bf_hi(u);
    }
  }
  float inv = 1.0f / fmaxf((float)d, 1.0f);
  uint* op = reinterpret_cast<uint*>(out + (size_t)node * K + baseoff);
#pragma unroll
  for (int w = 0; w < CW; ++w) {
    uint lo = f2bf(acc[2 * w] * inv);
    uint hi = f2bf(acc[2 * w + 1] * inv);
    op[w] = lo | (hi << 16);
  }
}

// ---------------- fused SAGE GEMM ----------------
// block = 4 waves; block owns 32 rows; wave w owns 64 cols (4 16x16 frags),
// 2 row-subtiles (m) x 4 col-frags (f) => acc[2][4], K-loop in steps of 32.
// l2norm row-sums cross the 4 waves -> LDS reduction.
template <int K, bool LAST>
__global__ __launch_bounds__(256) void gemm_kernel(const ushort* __restrict__ A,
                                                   const ushort* __restrict__ G,
                                                   const ushort* __restrict__ Bs,
                                                   const ushort* __restrict__ Bn,
                                                   const float* __restrict__ bias,
                                                   void* __restrict__ outv) {
  const int w = threadIdx.x >> 6;       // wave id = col group
  const int lane = threadIdx.x & 63;
  const int lj = lane & 15, lg = lane >> 4;
  const int r0 = blockIdx.x * 32;
  __shared__ float red[4][2][4][4];     // [wave][m][lg][e]

  const ushort* ap0 = A + (size_t)(r0 + lj) * K + lg * 8;
  const ushort* ap1 = A + (size_t)(r0 + 16 + lj) * K + lg * 8;
  const ushort* gp0 = G + (size_t)(r0 + lj) * K + lg * 8;
  const ushort* gp1 = G + (size_t)(r0 + 16 + lj) * K + lg * 8;
  const int cfbase = w * 4;             // global col-frag base
  const ushort* bsp = Bs + cfbase * 512 + lj * 32 + lg * 8;
  const ushort* bnp = Bn + cfbase * 512 + lj * 32 + lg * 8;

  f32x4 acc[2][4];
#pragma unroll
  for (int m = 0; m < 2; ++m)
#pragma unroll
    for (int f = 0; f < 4; ++f) acc[m][f] = (f32x4){0.f, 0.f, 0.f, 0.f};

  for (int kc = 0; kc < K / 32; ++kc) {
    bf16x8 as0 = *reinterpret_cast<const bf16x8*>(ap0 + kc * 32);
    bf16x8 as1 = *reinterpret_cast<const bf16x8*>(ap1 + kc * 32);
    bf16x8 an0 = *reinterpret_cast<const bf16x8*>(gp0 + kc * 32);
    bf16x8 an1 = *reinterpret_cast<const bf16x8*>(gp1 + kc * 32);
    const ushort* bs = bsp + kc * 8192;
    const ushort* bn = bnp + kc * 8192;
#pragma unroll
    for (int f = 0; f < 4; ++f) {
      bf16x8 b1 = *reinterpret_cast<const bf16x8*>(bs + f * 512);
      bf16x8 b2 = *reinterpret_cast<const bf16x8*>(bn + f * 512);
      acc[0][f] = __builtin_amdgcn_mfma_f32_16x16x32_bf16(as0, b1, acc[0][f], 0, 0, 0);
      acc[1][f] = __builtin_amdgcn_mfma_f32_16x16x32_bf16(as1, b1, acc[1][f], 0, 0, 0);
      acc[0][f] = __builtin_amdgcn_mfma_f32_16x16x32_bf16(an0, b2, acc[0][f], 0, 0, 0);
      acc[1][f] = __builtin_amdgcn_mfma_f32_16x16x32_bf16(an1, b2, acc[1][f], 0, 0, 0);
    }
  }

  float bv[4];
#pragma unroll
  for (int f = 0; f < 4; ++f) bv[f] = bias[(cfbase + f) * 16 + lj];

  if (LAST) {
    float* out = reinterpret_cast<float*>(outv);
#pragma unroll
    for (int m = 0; m < 2; ++m)
#pragma unroll
      for (int f = 0; f < 4; ++f)
#pragma unroll
        for (int e = 0; e < 4; ++e) {
          int row = r0 + m * 16 + lg * 4 + e;
          if (row < N_NODES)
            out[(size_t)row * 256 + (cfbase + f) * 16 + lj] = acc[m][f][e] + bv[f];
        }
  } else {
    // relu + partial row-sumsq
    float s[2][4];
#pragma unroll
    for (int m = 0; m < 2; ++m)
#pragma unroll
      for (int e = 0; e < 4; ++e) s[m][e] = 0.f;
#pragma unroll
    for (int m = 0; m < 2; ++m)
#pragma unroll
      for (int f = 0; f < 4; ++f)
#pragma unroll
        for (int e = 0; e < 4; ++e) {
          float v = fmaxf(acc[m][f][e] + bv[f], 0.0f);
          acc[m][f][e] = v;
          s[m][e] += v * v;
        }
    // reduce over the 16 lj lanes
#pragma unroll
    for (int m = 0; m < 2; ++m)
#pragma unroll
      for (int e = 0; e < 4; ++e) {
        float t = s[m][e];
        t += __shfl_xor(t, 1);
        t += __shfl_xor(t, 2);
        t += __shfl_xor(t, 4);
        t += __shfl_xor(t, 8);
        s[m][e] = t;
      }
    // cross-wave reduction via LDS
    if (lj == 0) {
#pragma unroll
      for (int m = 0; m < 2; ++m)
#pragma unroll
        for (int e = 0; e < 4; ++e) red[w][m][lg][e] = s[m][e];
    }
    __syncthreads();
    float inv[2][4];
#pragma unroll
    for (int m = 0; m < 2; ++m)
#pragma unroll
      for (int e = 0; e < 4; ++e) {
        float t = red[0][m][lg][e] + red[1][m][lg][e] + red[2][m][lg][e] + red[3][m][lg][e];
        inv[m][e] = 1.0f / fmaxf(sqrtf(t), 1e-12f);
      }
    ushort* out = reinterpret_cast<ushort*>(outv);
#pragma unroll
    for (int m = 0; m < 2; ++m)
#pragma unroll
      for (int f = 0; f < 4; ++f)
#pragma unroll
        for (int e = 0; e < 4; ++e) {
          int row = r0 + m * 16 + lg * 4 + e;
          if (row < N_NODES)
            out[(size_t)row * 256 + (cfbase + f) * 16 + lj] = f2bf(acc[m][f][e] * inv[m][e]);
        }
  }
}

// ---------------- launch ----------------
extern "C" void kernel_launch(void* const* d_in, const int* in_sizes, int n_in,
                              void* d_out, int out_size, void* d_ws, size_t ws_size,
                              hipStream_t stream) {
  const float* x   = (const float*)d_in[0];
  const int*   src = (const int*)d_in[1];
  const int*   dst = (const int*)d_in[2];
  const float* Ws0 = (const float*)d_in[3];
  const float* Wn0 = (const float*)d_in[4];
  const float* b0  = (const float*)d_in[5];
  const float* Ws1 = (const float*)d_in[6];
  const float* Wn1 = (const float*)d_in[7];
  const float* b1  = (const float*)d_in[8];
  const float* Ws2 = (const float*)d_in[9];
  const float* Wn2 = (const float*)d_in[10];
  const float* b2  = (const float*)d_in[11];

  uintptr_t p = ((uintptr_t)d_ws + 255) & ~(uintptr_t)255;
  auto carve = [&](size_t bytes) {
    void* r = (void*)p;
    p += (bytes + 255) & ~(size_t)255;
    return r;
  };
  ushort* h0   = (ushort*)carve((size_t)N_NODES * DIM_IN * 2);
  ushort* agg  = (ushort*)carve((size_t)N_NODES * DIM_IN * 2);
  ushort* h1   = (ushort*)carve((size_t)N_NODES * DIM_H * 2);
  ushort* h2   = (ushort*)carve((size_t)N_NODES * DIM_H * 2);
  ushort* Ws0p = (ushort*)carve((size_t)DIM_IN * 256 * 2);
  ushort* Wn0p = (ushort*)carve((size_t)DIM_IN * 256 * 2);
  ushort* Ws1p = (ushort*)carve((size_t)DIM_H * 256 * 2);
  ushort* Wn1p = (ushort*)carve((size_t)DIM_H * 256 * 2);
  ushort* Ws2p = (ushort*)carve((size_t)DIM_H * 256 * 2);
  ushort* Wn2p = (ushort*)carve((size_t)DIM_H * 256 * 2);
  int* deg    = (int*)carve((size_t)N_NODES * 4);
  int* rowptr = (int*)carve((size_t)N_NODES * 4);
  int* cursor = (int*)carve((size_t)N_NODES * 4);
  int* csr    = (int*)carve((size_t)N_EDGES * 4);

  hipMemsetAsync(deg, 0, (size_t)N_NODES * 4, stream);

  {
    int n4 = N_NODES * DIM_IN / 4;
    log1p_kernel<<<(n4 + 255) / 256, 256, 0, stream>>>(x, h0, n4);
  }
  hist_kernel<<<(N_EDGES + 255) / 256, 256, 0, stream>>>(dst, deg, N_EDGES);
  scan_kernel<<<1, 1024, 0, stream>>>(deg, rowptr, cursor, N_NODES);
  fill_kernel<<<(N_EDGES + 255) / 256, 256, 0, stream>>>(src, dst, cursor, csr, N_EDGES);
  pack_w_kernel<<<(DIM_IN * 256 + 255) / 256, 256, 0, stream>>>(Ws0, Ws0p, DIM_IN);
  pack_w_kernel<<<(DIM_IN * 256 + 255) / 256, 256, 0, stream>>>(Wn0, Wn0p, DIM_IN);
  pack_w_kernel<<<(DIM_H * 256 + 255) / 256, 256, 0, stream>>>(Ws1, Ws1p, DIM_H);
  pack_w_kernel<<<(DIM_H * 256 + 255) / 256, 256, 0, stream>>>(Wn1, Wn1p, DIM_H);
  pack_w_kernel<<<(DIM_H * 256 + 255) / 256, 256, 0, stream>>>(Ws2, Ws2p, DIM_H);
  pack_w_kernel<<<(DIM_H * 256 + 255) / 256, 256, 0, stream>>>(Wn2, Wn2p, DIM_H);

  const int aggBlocks  = (N_NODES + 3) / 4;
  const int gemmBlocks = (N_NODES + 31) / 32;

  agg_kernel<DIM_IN><<<aggBlocks, 256, 0, stream>>>(h0, rowptr, deg, csr, agg);
  gemm_kernel<DIM_IN, false><<<gemmBlocks, 256, 0, stream>>>(h0, agg, Ws0p, Wn0p, b0, h1);
  agg_kernel<DIM_H><<<aggBlocks, 256, 0, stream>>>(h1, rowptr, deg, csr, agg);
  gemm_kernel<DIM_H, false><<<gemmBlocks, 256, 0, stream>>>(h1, agg, Ws1p, Wn1p, b1, h2);
  agg_kernel<DIM_H><<<aggBlocks, 256, 0, stream>>>(h2, rowptr, deg, csr, agg);
  gemm_kernel<DIM_H, true><<<gemmBlocks, 256, 0, stream>>>(h2, agg, Ws2p, Wn2p, b2, d_out);
}

// Round 3
// 513.355 us; speedup vs baseline: 1.5665x; 1.2105x over previous
//
#include <hip/hip_runtime.h>
#include <hip/hip_bf16.h>

#define N_NODES 50000
#define N_EDGES 800000
#define DIM_IN  384
#define DIM_H   256

typedef __bf16 bf16x8 __attribute__((ext_vector_type(8)));
typedef float  f32x4  __attribute__((ext_vector_type(4)));

static __device__ __forceinline__ ushort f2bf(float f) {
  uint u = __float_as_uint(f);
  u += 0x7fffu + ((u >> 16) & 1u);
  return (ushort)(u >> 16);
}
static __device__ __forceinline__ float bf_lo(uint u) { return __uint_as_float(u << 16); }
static __device__ __forceinline__ float bf_hi(uint u) { return __uint_as_float(u & 0xffff0000u); }

typedef const __attribute__((address_space(1))) void* gas_p;
typedef __attribute__((address_space(3))) void* las_p;
static __device__ __forceinline__ void gload16(const void* g, void* l) {
  __builtin_amdgcn_global_load_lds((gas_p)g, (las_p)l, 16, 0, 0);
}

// ---------------- h0 = log1p(x), f32 -> bf16 ----------------
__global__ void log1p_kernel(const float* __restrict__ x, ushort* __restrict__ h, int n4) {
  int i = blockIdx.x * 256 + threadIdx.x;
  if (i >= n4) return;
  float4 v = reinterpret_cast<const float4*>(x)[i];
  ushort4 o;
  o.x = f2bf(log1pf(v.x));
  o.y = f2bf(log1pf(v.y));
  o.z = f2bf(log1pf(v.z));
  o.w = f2bf(log1pf(v.w));
  reinterpret_cast<ushort4*>(h)[i] = o;
}

// ---------------- CSR build ----------------
__global__ void hist_kernel(const int* __restrict__ dst, int* __restrict__ deg, int e) {
  int i = blockIdx.x * 256 + threadIdx.x;
  if (i < e) atomicAdd(&deg[dst[i]], 1);
}

__global__ void scan_kernel(const int* __restrict__ deg, int* __restrict__ rowptr,
                            int* __restrict__ cursor, int n) {
  __shared__ int buf[1024];
  __shared__ int s_carry;
  int t = threadIdx.x;
  if (t == 0) s_carry = 0;
  __syncthreads();
  for (int base = 0; base < n; base += 1024) {
    int v = (base + t < n) ? deg[base + t] : 0;
    buf[t] = v;
    __syncthreads();
    int x = v;
    for (int off = 1; off < 1024; off <<= 1) {
      int y = (t >= off) ? buf[t - off] : 0;
      __syncthreads();
      x += y;
      buf[t] = x;
      __syncthreads();
    }
    int excl = x - v;
    int c = s_carry;
    if (base + t < n) { rowptr[base + t] = c + excl; cursor[base + t] = c + excl; }
    __syncthreads();
    if (t == 1023) s_carry = c + x;
    __syncthreads();
  }
}

__global__ void fill_kernel(const int* __restrict__ src, const int* __restrict__ dst,
                            int* __restrict__ cursor, int* __restrict__ csr, int e) {
  int i = blockIdx.x * 256 + threadIdx.x;
  if (i >= e) return;
  int d = dst[i];
  int p = atomicAdd(&cursor[d], 1);
  csr[p] = src[i];
}

// ---------------- weight prepack: W[k][col] f32 -> swizzled staged layout ----------------
// Bpack[(kc*256 + col)*32 + kgs*8 + e] = bf16(W[(kc*32 + kgd*8 + e)*256 + col])
// with kgd = kgs ^ ((col>>1)&3)  (XOR swizzle so ds_read_b128 is conflict-free)
__global__ void pack_w_kernel(const float* __restrict__ W, ushort* __restrict__ out, int K) {
  int idx = blockIdx.x * 256 + threadIdx.x;
  if (idx >= K * 256) return;
  int k = idx >> 8, col = idx & 255;
  int kc = k >> 5, kgd = (k >> 3) & 3, e = k & 7;
  int kgs = kgd ^ ((col >> 1) & 3);
  out[((size_t)kc * 256 + col) * 32 + kgs * 8 + e] = f2bf(W[idx]);
}

// ---------------- mean aggregation: half-wave (32 lanes) per dst node ----------------
template <int K>
__global__ __launch_bounds__(256) void agg_kernel(const ushort* __restrict__ h,
                                                  const int* __restrict__ rowptr,
                                                  const int* __restrict__ deg,
                                                  const int* __restrict__ csr,
                                                  ushort* __restrict__ out) {
  int node = blockIdx.x * 8 + (threadIdx.x >> 5);
  if (node >= N_NODES) return;
  int hl = threadIdx.x & 31;
  constexpr int CPL = K / 32;   // bf16 per lane: 8 (K=256) or 12 (K=384)
  int start = rowptr[node];
  int d = deg[node];
  float acc[CPL];
#pragma unroll
  for (int i = 0; i < CPL; ++i) acc[i] = 0.0f;

  auto accum = [&](uint u, int i) {
    acc[2 * i]     += bf_lo(u);
    acc[2 * i + 1] += bf_hi(u);
  };
  auto load_row = [&](int s, uint* r) {
    const ushort* base = h + (size_t)s * K + hl * CPL;
    if constexpr (K == 256) {
      uint4 q = *reinterpret_cast<const uint4*>(base);
      r[0] = q.x; r[1] = q.y; r[2] = q.z; r[3] = q.w;
    } else {
      uint2 q0 = *reinterpret_cast<const uint2*>(base);
      uint2 q1 = *reinterpret_cast<const uint2*>(base + 4);
      uint2 q2 = *reinterpret_cast<const uint2*>(base + 8);
      r[0] = q0.x; r[1] = q0.y; r[2] = q1.x; r[3] = q1.y; r[4] = q2.x; r[5] = q2.y;
    }
  };
  constexpr int DW = CPL / 2;

  int e = 0;
  for (; e + 4 <= d; e += 4) {
    int s0 = csr[start + e], s1 = csr[start + e + 1];
    int s2 = csr[start + e + 2], s3 = csr[start + e + 3];
    uint r0[DW], r1[DW], r2[DW], r3[DW];
    load_row(s0, r0); load_row(s1, r1); load_row(s2, r2); load_row(s3, r3);
#pragma unroll
    for (int i = 0; i < DW; ++i) { accum(r0[i], i); accum(r1[i], i); accum(r2[i], i); accum(r3[i], i); }
  }
  for (; e < d; ++e) {
    int s = csr[start + e];
    uint r[DW];
    load_row(s, r);
#pragma unroll
    for (int i = 0; i < DW; ++i) accum(r[i], i);
  }

  float inv = 1.0f / fmaxf((float)d, 1.0f);
  uint o[DW];
#pragma unroll
  for (int i = 0; i < DW; ++i) {
    uint lo = f2bf(acc[2 * i] * inv);
    uint hi = f2bf(acc[2 * i + 1] * inv);
    o[i] = lo | (hi << 16);
  }
  ushort* ob = out + (size_t)node * K + hl * CPL;
  if constexpr (K == 256) {
    *reinterpret_cast<uint4*>(ob) = make_uint4(o[0], o[1], o[2], o[3]);
  } else {
    *reinterpret_cast<uint2*>(ob)     = make_uint2(o[0], o[1]);
    *reinterpret_cast<uint2*>(ob + 4) = make_uint2(o[2], o[3]);
    *reinterpret_cast<uint2*>(ob + 8) = make_uint2(o[4], o[5]);
  }
}

// ---------------- fused SAGE GEMM, LDS-staged double-buffered ----------------
// block = 4 waves, tile 128 rows x 256 cols (full N). wave (wm,wn) = 64 rows x 128 cols,
// acc[4][8]. K-loop concatenates self-phase (A,Bs) then neigh-phase (G,Bn), steps of 32.
// A-slice (128x32 = 8KB) + B-slice (32x256 = 16KB) staged via global_load_lds (dbuf).
// XOR swizzle kgs = kg ^ ((row|col >>1)&3): A pre-swizzled at the global SOURCE address,
// B prepacked swizzled -> all ds_read_b128 conflict-free (2-way max).
template <int K, bool LAST>
__global__ __launch_bounds__(256, 2) void gemm_kernel(const ushort* __restrict__ A,
                                                      const ushort* __restrict__ G,
                                                      const ushort* __restrict__ Bs,
                                                      const ushort* __restrict__ Bn,
                                                      const float* __restrict__ bias,
                                                      void* __restrict__ outv) {
  constexpr int KC = K / 32;
  constexpr int NT = 2 * KC;
  __shared__ ushort Al[2][4096];   // 2 x 8KB  : [row][kgs][8]
  __shared__ ushort Bl[2][8192];   // 2 x 16KB : [col][kgs][8]
  __shared__ float red[2][2][4][4][4];  // [wn][wm][mf][lg][e]

  const int tid = threadIdx.x;
  const int wv = tid >> 6, lane = tid & 63, lj = lane & 15, lg = lane >> 4;
  const int wm = wv >> 1, wn = wv & 1;
  const int r0 = blockIdx.x * 128;

  // A staging descriptors (2 chunks/thread)
  int grow[2], akgd[2];
#pragma unroll
  for (int j = 0; j < 2; ++j) {
    int d = tid + j * 256;
    int row = d >> 2, kgs = d & 3;
    akgd[j] = kgs ^ ((row >> 1) & 3);
    int r = r0 + row;
    grow[j] = r < N_NODES ? r : N_NODES - 1;
  }

  // read offsets (ushort units), conflict-free swizzled
  int aoff[4], boff[8];
#pragma unroll
  for (int mf = 0; mf < 4; ++mf) {
    int row = wm * 64 + mf * 16 + lj;
    aoff[mf] = row * 32 + (lg ^ ((row >> 1) & 3)) * 8;
  }
#pragma unroll
  for (int f = 0; f < 8; ++f) {
    int col = wn * 128 + f * 16 + lj;
    boff[f] = col * 32 + (lg ^ ((col >> 1) & 3)) * 8;
  }

  auto stage = [&](int t, int bb) {
    int p = t >= KC;
    int kc = t - p * KC;
    const ushort* Ap = p ? G : A;
    const ushort* Bp = p ? Bn : Bs;
#pragma unroll
    for (int j = 0; j < 2; ++j)
      gload16(Ap + (size_t)grow[j] * K + kc * 32 + akgd[j] * 8,
              (char*)&Al[bb][0] + j * 4096 + wv * 1024);
#pragma unroll
    for (int j = 0; j < 4; ++j)
      gload16(Bp + (size_t)kc * 8192 + (tid + j * 256) * 8,
              (char*)&Bl[bb][0] + j * 4096 + wv * 1024);
  };

  f32x4 acc[4][8];
#pragma unroll
  for (int mf = 0; mf < 4; ++mf)
#pragma unroll
    for (int f = 0; f < 8; ++f) acc[mf][f] = (f32x4){0.f, 0.f, 0.f, 0.f};

  stage(0, 0);
  __syncthreads();
  int b = 0;
  for (int t = 0; t < NT; ++t) {
    if (t + 1 < NT) stage(t + 1, b ^ 1);
    bf16x8 av[4], bv[8];
#pragma unroll
    for (int mf = 0; mf < 4; ++mf)
      av[mf] = *reinterpret_cast<const bf16x8*>(&Al[b][aoff[mf]]);
#pragma unroll
    for (int f = 0; f < 8; ++f)
      bv[f] = *reinterpret_cast<const bf16x8*>(&Bl[b][boff[f]]);
#pragma unroll
    for (int mf = 0; mf < 4; ++mf)
#pragma unroll
      for (int f = 0; f < 8; ++f)
        acc[mf][f] = __builtin_amdgcn_mfma_f32_16x16x32_bf16(av[mf], bv[f], acc[mf][f], 0, 0, 0);
    __syncthreads();
    b ^= 1;
  }

  float bvv[8];
#pragma unroll
  for (int f = 0; f < 8; ++f) bvv[f] = bias[wn * 128 + f * 16 + lj];

  if (LAST) {
    float* out = reinterpret_cast<float*>(outv);
#pragma unroll
    for (int mf = 0; mf < 4; ++mf)
#pragma unroll
      for (int f = 0; f < 8; ++f)
#pragma unroll
        for (int e = 0; e < 4; ++e) {
          int row = r0 + wm * 64 + mf * 16 + lg * 4 + e;
          if (row < N_NODES)
            out[(size_t)row * 256 + wn * 128 + f * 16 + lj] = acc[mf][f][e] + bvv[f];
        }
  } else {
    float s[4][4];
#pragma unroll
    for (int mf = 0; mf < 4; ++mf)
#pragma unroll
      for (int e = 0; e < 4; ++e) s[mf][e] = 0.f;
#pragma unroll
    for (int mf = 0; mf < 4; ++mf)
#pragma unroll
      for (int f = 0; f < 8; ++f)
#pragma unroll
        for (int e = 0; e < 4; ++e) {
          float v = fmaxf(acc[mf][f][e] + bvv[f], 0.0f);
          acc[mf][f][e] = v;
          s[mf][e] += v * v;
        }
#pragma unroll
    for (int mf = 0; mf < 4; ++mf)
#pragma unroll
      for (int e = 0; e < 4; ++e) {
        float t2 = s[mf][e];
        t2 += __shfl_xor(t2, 1);
        t2 += __shfl_xor(t2, 2);
        t2 += __shfl_xor(t2, 4);
        t2 += __shfl_xor(t2, 8);
        s[mf][e] = t2;
      }
    if (lj == 0) {
#pragma unroll
      for (int mf = 0; mf < 4; ++mf)
#pragma unroll
        for (int e = 0; e < 4; ++e) red[wn][wm][mf][lg][e] = s[mf][e];
    }
    __syncthreads();
    ushort* out = reinterpret_cast<ushort*>(outv);
#pragma unroll
    for (int mf = 0; mf < 4; ++mf)
#pragma unroll
      for (int e = 0; e < 4; ++e) {
        float t2 = red[0][wm][mf][lg][e] + red[1][wm][mf][lg][e];
        float inv = 1.0f / fmaxf(sqrtf(t2), 1e-12f);
        int row = r0 + wm * 64 + mf * 16 + lg * 4 + e;
        if (row < N_NODES) {
#pragma unroll
          for (int f = 0; f < 8; ++f)
            out[(size_t)row * 256 + wn * 128 + f * 16 + lj] = f2bf(acc[mf][f][e] * inv);
        }
      }
  }
}

// ---------------- launch ----------------
extern "C" void kernel_launch(void* const* d_in, const int* in_sizes, int n_in,
                              void* d_out, int out_size, void* d_ws, size_t ws_size,
                              hipStream_t stream) {
  const float* x   = (const float*)d_in[0];
  const int*   src = (const int*)d_in[1];
  const int*   dst = (const int*)d_in[2];
  const float* Ws0 = (const float*)d_in[3];
  const float* Wn0 = (const float*)d_in[4];
  const float* b0  = (const float*)d_in[5];
  const float* Ws1 = (const float*)d_in[6];
  const float* Wn1 = (const float*)d_in[7];
  const float* b1  = (const float*)d_in[8];
  const float* Ws2 = (const float*)d_in[9];
  const float* Wn2 = (const float*)d_in[10];
  const float* b2  = (const float*)d_in[11];

  uintptr_t p = ((uintptr_t)d_ws + 255) & ~(uintptr_t)255;
  auto carve = [&](size_t bytes) {
    void* r = (void*)p;
    p += (bytes + 255) & ~(size_t)255;
    return r;
  };
  ushort* h0   = (ushort*)carve((size_t)N_NODES * DIM_IN * 2);
  ushort* agg  = (ushort*)carve((size_t)N_NODES * DIM_IN * 2);
  ushort* h1   = (ushort*)carve((size_t)N_NODES * DIM_H * 2);
  ushort* h2   = (ushort*)carve((size_t)N_NODES * DIM_H * 2);
  ushort* Ws0p = (ushort*)carve((size_t)DIM_IN * 256 * 2);
  ushort* Wn0p = (ushort*)carve((size_t)DIM_IN * 256 * 2);
  ushort* Ws1p = (ushort*)carve((size_t)DIM_H * 256 * 2);
  ushort* Wn1p = (ushort*)carve((size_t)DIM_H * 256 * 2);
  ushort* Ws2p = (ushort*)carve((size_t)DIM_H * 256 * 2);
  ushort* Wn2p = (ushort*)carve((size_t)DIM_H * 256 * 2);
  int* deg    = (int*)carve((size_t)N_NODES * 4);
  int* rowptr = (int*)carve((size_t)N_NODES * 4);
  int* cursor = (int*)carve((size_t)N_NODES * 4);
  int* csr    = (int*)carve((size_t)N_EDGES * 4);

  hipMemsetAsync(deg, 0, (size_t)N_NODES * 4, stream);

  {
    int n4 = N_NODES * DIM_IN / 4;
    log1p_kernel<<<(n4 + 255) / 256, 256, 0, stream>>>(x, h0, n4);
  }
  hist_kernel<<<(N_EDGES + 255) / 256, 256, 0, stream>>>(dst, deg, N_EDGES);
  scan_kernel<<<1, 1024, 0, stream>>>(deg, rowptr, cursor, N_NODES);
  fill_kernel<<<(N_EDGES + 255) / 256, 256, 0, stream>>>(src, dst, cursor, csr, N_EDGES);
  pack_w_kernel<<<(DIM_IN * 256 + 255) / 256, 256, 0, stream>>>(Ws0, Ws0p, DIM_IN);
  pack_w_kernel<<<(DIM_IN * 256 + 255) / 256, 256, 0, stream>>>(Wn0, Wn0p, DIM_IN);
  pack_w_kernel<<<(DIM_H * 256 + 255) / 256, 256, 0, stream>>>(Ws1, Ws1p, DIM_H);
  pack_w_kernel<<<(DIM_H * 256 + 255) / 256, 256, 0, stream>>>(Wn1, Wn1p, DIM_H);
  pack_w_kernel<<<(DIM_H * 256 + 255) / 256, 256, 0, stream>>>(Ws2, Ws2p, DIM_H);
  pack_w_kernel<<<(DIM_H * 256 + 255) / 256, 256, 0, stream>>>(Wn2, Wn2p, DIM_H);

  const int aggBlocks  = (N_NODES + 7) / 8;
  const int gemmBlocks = (N_NODES + 127) / 128;

  agg_kernel<DIM_IN><<<aggBlocks, 256, 0, stream>>>(h0, rowptr, deg, csr, agg);
  gemm_kernel<DIM_IN, false><<<gemmBlocks, 256, 0, stream>>>(h0, agg, Ws0p, Wn0p, b0, h1);
  agg_kernel<DIM_H><<<aggBlocks, 256, 0, stream>>>(h1, rowptr, deg, csr, agg);
  gemm_kernel<DIM_H, false><<<gemmBlocks, 256, 0, stream>>>(h1, agg, Ws1p, Wn1p, b1, h2);
  agg_kernel<DIM_H><<<aggBlocks, 256, 0, stream>>>(h2, rowptr, deg, csr, agg);
  gemm_kernel<DIM_H, true><<<gemmBlocks, 256, 0, stream>>>(h2, agg, Ws2p, Wn2p, b2, d_out);
}

// Round 4
// 408.875 us; speedup vs baseline: 1.9668x; 1.2555x over previous
//
#include <hip/hip_runtime.h>
#include <hip/hip_bf16.h>

#define N_NODES 50000
#define N_EDGES 800000
#define DIM_IN  384
#define DIM_H   256

typedef __bf16 bf16x8 __attribute__((ext_vector_type(8)));
typedef float  f32x4  __attribute__((ext_vector_type(4)));

static __device__ __forceinline__ ushort f2bf(float f) {
  uint u = __float_as_uint(f);
  u += 0x7fffu + ((u >> 16) & 1u);
  return (ushort)(u >> 16);
}
static __device__ __forceinline__ float bf_lo(uint u) { return __uint_as_float(u << 16); }
static __device__ __forceinline__ float bf_hi(uint u) { return __uint_as_float(u & 0xffff0000u); }

typedef const __attribute__((address_space(1))) void* gas_p;
typedef __attribute__((address_space(3))) void* las_p;
static __device__ __forceinline__ void gload16(const void* g, void* l) {
  __builtin_amdgcn_global_load_lds((gas_p)g, (las_p)l, 16, 0, 0);
}

// ---------------- h0 = log1p(x), f32 -> bf16 ----------------
__global__ void log1p_kernel(const float* __restrict__ x, ushort* __restrict__ h, int n4) {
  int i = blockIdx.x * 256 + threadIdx.x;
  if (i >= n4) return;
  float4 v = reinterpret_cast<const float4*>(x)[i];
  ushort4 o;
  o.x = f2bf(log1pf(v.x));
  o.y = f2bf(log1pf(v.y));
  o.z = f2bf(log1pf(v.z));
  o.w = f2bf(log1pf(v.w));
  reinterpret_cast<ushort4*>(h)[i] = o;
}

// ---------------- CSR build ----------------
__global__ void hist_kernel(const int* __restrict__ dst, int* __restrict__ deg, int e) {
  int i = blockIdx.x * 256 + threadIdx.x;
  if (i < e) atomicAdd(&deg[dst[i]], 1);
}

// hierarchical scan: per-block exclusive scan + block sums
__global__ void scan1_kernel(const int* __restrict__ deg, int* __restrict__ tmp,
                             int* __restrict__ bsum) {
  __shared__ int buf[256];
  int t = threadIdx.x, i = blockIdx.x * 256 + t;
  int v = (i < N_NODES) ? deg[i] : 0;
  buf[t] = v;
  __syncthreads();
  int x = v;
#pragma unroll
  for (int off = 1; off < 256; off <<= 1) {
    int y = (t >= off) ? buf[t - off] : 0;
    __syncthreads();
    x += y;
    buf[t] = x;
    __syncthreads();
  }
  if (i < N_NODES) tmp[i] = x - v;
  if (t == 255) bsum[blockIdx.x] = x;
}

__global__ void scan2_kernel(int* __restrict__ bsum, int nb) {
  __shared__ int buf[256];
  int t = threadIdx.x;
  int v = (t < nb) ? bsum[t] : 0;
  buf[t] = v;
  __syncthreads();
  int x = v;
#pragma unroll
  for (int off = 1; off < 256; off <<= 1) {
    int y = (t >= off) ? buf[t - off] : 0;
    __syncthreads();
    x += y;
    buf[t] = x;
    __syncthreads();
  }
  if (t < nb) bsum[t] = x - v;
}

__global__ void scan3_kernel(const int* __restrict__ tmp, const int* __restrict__ bsum,
                             int* __restrict__ rowptr, int* __restrict__ cursor) {
  int i = blockIdx.x * 256 + threadIdx.x;
  if (i >= N_NODES) return;
  int r = tmp[i] + bsum[i >> 8];
  rowptr[i] = r;
  cursor[i] = r;
}

__global__ void fill_kernel(const int* __restrict__ src, const int* __restrict__ dst,
                            int* __restrict__ cursor, int* __restrict__ csr, int e) {
  int i = blockIdx.x * 256 + threadIdx.x;
  if (i >= e) return;
  int d = dst[i];
  int p = atomicAdd(&cursor[d], 1);
  csr[p] = src[i];
}

// ---------------- weight prepack (all 6 weights in one kernel) ----------------
// out[(kc*256 + col)*32 + kgs*8 + e] = bf16(W[(kc*32 + kgd*8 + e)*256 + col]),
// kgd = kgs ^ ((col>>1)&3)
static __device__ __forceinline__ void pack_one(const float* W, ushort* out, int local) {
  int k = local >> 8, col = local & 255;
  int kc = k >> 5, kgd = (k >> 3) & 3, e = k & 7;
  int kgs = kgd ^ ((col >> 1) & 3);
  out[((size_t)kc * 256 + col) * 32 + kgs * 8 + e] = f2bf(W[local]);
}

__global__ void pack_all_kernel(const float* W0s, const float* W0n, const float* W1s,
                                const float* W1n, const float* W2s, const float* W2n,
                                ushort* o0s, ushort* o0n, ushort* o1s, ushort* o1n,
                                ushort* o2s, ushort* o2n) {
  int idx = blockIdx.x * 256 + threadIdx.x;
  const int SZ0 = DIM_IN * 256;   // 98304
  const int SZ1 = DIM_H * 256;    // 65536
  if (idx < SZ0) pack_one(W0s, o0s, idx);
  else if (idx < 2 * SZ0) pack_one(W0n, o0n, idx - SZ0);
  else {
    int j = idx - 2 * SZ0;
    int w = j / SZ1, local = j - w * SZ1;
    if (w == 0) pack_one(W1s, o1s, local);
    else if (w == 1) pack_one(W1n, o1n, local);
    else if (w == 2) pack_one(W2s, o2s, local);
    else if (w == 3) pack_one(W2n, o2n, local);
  }
}

// ---------------- mean aggregation (plain, K=256): half-wave per node ----------------
__global__ __launch_bounds__(256) void agg_kernel(const ushort* __restrict__ h,
                                                  const int* __restrict__ rowptr,
                                                  const int* __restrict__ deg,
                                                  const int* __restrict__ csr,
                                                  ushort* __restrict__ out) {
  int node = blockIdx.x * 8 + (threadIdx.x >> 5);
  if (node >= N_NODES) return;
  int hl = threadIdx.x & 31;
  int start = rowptr[node];
  int d = deg[node];
  float acc[8];
#pragma unroll
  for (int i = 0; i < 8; ++i) acc[i] = 0.0f;

  auto accum = [&](uint u, int i) {
    acc[2 * i]     += bf_lo(u);
    acc[2 * i + 1] += bf_hi(u);
  };
  int e = 0;
  for (; e + 4 <= d; e += 4) {
    int s0 = csr[start + e], s1 = csr[start + e + 1];
    int s2 = csr[start + e + 2], s3 = csr[start + e + 3];
    uint4 q0 = *reinterpret_cast<const uint4*>(h + (size_t)s0 * 256 + hl * 8);
    uint4 q1 = *reinterpret_cast<const uint4*>(h + (size_t)s1 * 256 + hl * 8);
    uint4 q2 = *reinterpret_cast<const uint4*>(h + (size_t)s2 * 256 + hl * 8);
    uint4 q3 = *reinterpret_cast<const uint4*>(h + (size_t)s3 * 256 + hl * 8);
    accum(q0.x, 0); accum(q0.y, 1); accum(q0.z, 2); accum(q0.w, 3);
    accum(q1.x, 0); accum(q1.y, 1); accum(q1.z, 2); accum(q1.w, 3);
    accum(q2.x, 0); accum(q2.y, 1); accum(q2.z, 2); accum(q2.w, 3);
    accum(q3.x, 0); accum(q3.y, 1); accum(q3.z, 2); accum(q3.w, 3);
  }
  for (; e < d; ++e) {
    int s = csr[start + e];
    uint4 q = *reinterpret_cast<const uint4*>(h + (size_t)s * 256 + hl * 8);
    accum(q.x, 0); accum(q.y, 1); accum(q.z, 2); accum(q.w, 3);
  }

  float inv = 1.0f / fmaxf((float)d, 1.0f);
  uint o[4];
#pragma unroll
  for (int i = 0; i < 4; ++i) {
    uint lo = f2bf(acc[2 * i] * inv);
    uint hi = f2bf(acc[2 * i + 1] * inv);
    o[i] = lo | (hi << 16);
  }
  *reinterpret_cast<uint4*>(out + (size_t)node * 256 + hl * 8) = make_uint4(o[0], o[1], o[2], o[3]);
}

// ---------------- fused layer-0 aggregation: out = l2norm(relu(S + mean(Y[src]))) ----------------
__global__ __launch_bounds__(256) void agg_fused_kernel(const ushort* __restrict__ Y,
                                                        const ushort* __restrict__ S,
                                                        const int* __restrict__ rowptr,
                                                        const int* __restrict__ deg,
                                                        const int* __restrict__ csr,
                                                        ushort* __restrict__ out) {
  int node = blockIdx.x * 8 + (threadIdx.x >> 5);
  if (node >= N_NODES) return;
  int hl = threadIdx.x & 31;
  int start = rowptr[node];
  int d = deg[node];
  float acc[8];
#pragma unroll
  for (int i = 0; i < 8; ++i) acc[i] = 0.0f;

  auto accum = [&](uint u, int i) {
    acc[2 * i]     += bf_lo(u);
    acc[2 * i + 1] += bf_hi(u);
  };
  int e = 0;
  for (; e + 4 <= d; e += 4) {
    int s0 = csr[start + e], s1 = csr[start + e + 1];
    int s2 = csr[start + e + 2], s3 = csr[start + e + 3];
    uint4 q0 = *reinterpret_cast<const uint4*>(Y + (size_t)s0 * 256 + hl * 8);
    uint4 q1 = *reinterpret_cast<const uint4*>(Y + (size_t)s1 * 256 + hl * 8);
    uint4 q2 = *reinterpret_cast<const uint4*>(Y + (size_t)s2 * 256 + hl * 8);
    uint4 q3 = *reinterpret_cast<const uint4*>(Y + (size_t)s3 * 256 + hl * 8);
    accum(q0.x, 0); accum(q0.y, 1); accum(q0.z, 2); accum(q0.w, 3);
    accum(q1.x, 0); accum(q1.y, 1); accum(q1.z, 2); accum(q1.w, 3);
    accum(q2.x, 0); accum(q2.y, 1); accum(q2.z, 2); accum(q2.w, 3);
    accum(q3.x, 0); accum(q3.y, 1); accum(q3.z, 2); accum(q3.w, 3);
  }
  for (; e < d; ++e) {
    int s = csr[start + e];
    uint4 q = *reinterpret_cast<const uint4*>(Y + (size_t)s * 256 + hl * 8);
    accum(q.x, 0); accum(q.y, 1); accum(q.z, 2); accum(q.w, 3);
  }

  float inv = 1.0f / fmaxf((float)d, 1.0f);
  uint4 sv = *reinterpret_cast<const uint4*>(S + (size_t)node * 256 + hl * 8);
  uint su[4] = {sv.x, sv.y, sv.z, sv.w};
  float v[8];
  float ssq = 0.f;
#pragma unroll
  for (int i = 0; i < 4; ++i) {
    float a = fmaxf(acc[2 * i] * inv + bf_lo(su[i]), 0.0f);
    float b = fmaxf(acc[2 * i + 1] * inv + bf_hi(su[i]), 0.0f);
    v[2 * i] = a; v[2 * i + 1] = b;
    ssq += a * a + b * b;
  }
  ssq += __shfl_xor(ssq, 1);
  ssq += __shfl_xor(ssq, 2);
  ssq += __shfl_xor(ssq, 4);
  ssq += __shfl_xor(ssq, 8);
  ssq += __shfl_xor(ssq, 16);
  float rn = 1.0f / fmaxf(sqrtf(ssq), 1e-12f);
  uint o[4];
#pragma unroll
  for (int i = 0; i < 4; ++i) {
    uint lo = f2bf(v[2 * i] * rn);
    uint hi = f2bf(v[2 * i + 1] * rn);
    o[i] = lo | (hi << 16);
  }
  *reinterpret_cast<uint4*>(out + (size_t)node * 256 + hl * 8) = make_uint4(o[0], o[1], o[2], o[3]);
}

// ---------------- fused SAGE GEMM, LDS-staged double-buffered ----------------
// MODE 0: out1 = bf16 l2norm(relu(A@Bs + G@Bn + b))   (mid layer)
// MODE 1: out1 = f32  A@Bs + G@Bn + b                 (last layer)
// MODE 2: out1 = bf16 A@Bs + b (S), out2 = bf16 A@Bn (Y)  (dual output, G==A)
template <int K, int MODE>
__global__ __launch_bounds__(256, 2) void gemm_kernel(const ushort* __restrict__ A,
                                                      const ushort* __restrict__ G,
                                                      const ushort* __restrict__ Bs,
                                                      const ushort* __restrict__ Bn,
                                                      const float* __restrict__ bias,
                                                      void* __restrict__ out1,
                                                      void* __restrict__ out2) {
  constexpr int KC = K / 32;
  constexpr int NT = 2 * KC;
  __shared__ ushort Al[2][4096];
  __shared__ ushort Bl[2][8192];
  __shared__ float red[2][2][4][4][4];

  const int tid = threadIdx.x;
  const int wv = tid >> 6, lane = tid & 63, lj = lane & 15, lg = lane >> 4;
  const int wm = wv >> 1, wn = wv & 1;
  const int r0 = blockIdx.x * 128;

  int grow[2], akgd[2];
#pragma unroll
  for (int j = 0; j < 2; ++j) {
    int d = tid + j * 256;
    int row = d >> 2, kgs = d & 3;
    akgd[j] = kgs ^ ((row >> 1) & 3);
    int r = r0 + row;
    grow[j] = r < N_NODES ? r : N_NODES - 1;
  }

  int aoff[4], boff[8];
#pragma unroll
  for (int mf = 0; mf < 4; ++mf) {
    int row = wm * 64 + mf * 16 + lj;
    aoff[mf] = row * 32 + (lg ^ ((row >> 1) & 3)) * 8;
  }
#pragma unroll
  for (int f = 0; f < 8; ++f) {
    int col = wn * 128 + f * 16 + lj;
    boff[f] = col * 32 + (lg ^ ((col >> 1) & 3)) * 8;
  }

  auto stage = [&](int t, int bb) {
    int p = t >= KC;
    int kc = t - p * KC;
    const ushort* Ap = p ? G : A;
    const ushort* Bp = p ? Bn : Bs;
#pragma unroll
    for (int j = 0; j < 2; ++j)
      gload16(Ap + (size_t)grow[j] * K + kc * 32 + akgd[j] * 8,
              (char*)&Al[bb][0] + j * 4096 + wv * 1024);
#pragma unroll
    for (int j = 0; j < 4; ++j)
      gload16(Bp + (size_t)kc * 8192 + (tid + j * 256) * 8,
              (char*)&Bl[bb][0] + j * 4096 + wv * 1024);
  };

  float bvv[8];
#pragma unroll
  for (int f = 0; f < 8; ++f) bvv[f] = bias[wn * 128 + f * 16 + lj];

  f32x4 acc[4][8];
#pragma unroll
  for (int mf = 0; mf < 4; ++mf)
#pragma unroll
    for (int f = 0; f < 8; ++f) acc[mf][f] = (f32x4){0.f, 0.f, 0.f, 0.f};

  stage(0, 0);
  __syncthreads();
  int b = 0;
  for (int t = 0; t < NT; ++t) {
    if (t + 1 < NT) stage(t + 1, b ^ 1);
    bf16x8 av[4], bv[8];
#pragma unroll
    for (int mf = 0; mf < 4; ++mf)
      av[mf] = *reinterpret_cast<const bf16x8*>(&Al[b][aoff[mf]]);
#pragma unroll
    for (int f = 0; f < 8; ++f)
      bv[f] = *reinterpret_cast<const bf16x8*>(&Bl[b][boff[f]]);
#pragma unroll
    for (int mf = 0; mf < 4; ++mf)
#pragma unroll
      for (int f = 0; f < 8; ++f)
        acc[mf][f] = __builtin_amdgcn_mfma_f32_16x16x32_bf16(av[mf], bv[f], acc[mf][f], 0, 0, 0);
    if constexpr (MODE == 2) {
      if (t == KC - 1) {
        // self-phase done: write S = acc + bias, reset acc for Y phase
        ushort* S = reinterpret_cast<ushort*>(out1);
#pragma unroll
        for (int mf = 0; mf < 4; ++mf)
#pragma unroll
          for (int e = 0; e < 4; ++e) {
            int row = r0 + wm * 64 + mf * 16 + lg * 4 + e;
            if (row < N_NODES) {
#pragma unroll
              for (int f = 0; f < 8; ++f)
                S[(size_t)row * 256 + wn * 128 + f * 16 + lj] = f2bf(acc[mf][f][e] + bvv[f]);
            }
          }
#pragma unroll
        for (int mf = 0; mf < 4; ++mf)
#pragma unroll
          for (int f = 0; f < 8; ++f) acc[mf][f] = (f32x4){0.f, 0.f, 0.f, 0.f};
      }
    }
    __syncthreads();
    b ^= 1;
  }

  if constexpr (MODE == 2) {
    ushort* Yp = reinterpret_cast<ushort*>(out2);
#pragma unroll
    for (int mf = 0; mf < 4; ++mf)
#pragma unroll
      for (int e = 0; e < 4; ++e) {
        int row = r0 + wm * 64 + mf * 16 + lg * 4 + e;
        if (row < N_NODES) {
#pragma unroll
          for (int f = 0; f < 8; ++f)
            Yp[(size_t)row * 256 + wn * 128 + f * 16 + lj] = f2bf(acc[mf][f][e]);
        }
      }
  } else if constexpr (MODE == 1) {
    float* out = reinterpret_cast<float*>(out1);
#pragma unroll
    for (int mf = 0; mf < 4; ++mf)
#pragma unroll
      for (int f = 0; f < 8; ++f)
#pragma unroll
        for (int e = 0; e < 4; ++e) {
          int row = r0 + wm * 64 + mf * 16 + lg * 4 + e;
          if (row < N_NODES)
            out[(size_t)row * 256 + wn * 128 + f * 16 + lj] = acc[mf][f][e] + bvv[f];
        }
  } else {
    float s[4][4];
#pragma unroll
    for (int mf = 0; mf < 4; ++mf)
#pragma unroll
      for (int e = 0; e < 4; ++e) s[mf][e] = 0.f;
#pragma unroll
    for (int mf = 0; mf < 4; ++mf)
#pragma unroll
      for (int f = 0; f < 8; ++f)
#pragma unroll
        for (int e = 0; e < 4; ++e) {
          float v = fmaxf(acc[mf][f][e] + bvv[f], 0.0f);
          acc[mf][f][e] = v;
          s[mf][e] += v * v;
        }
#pragma unroll
    for (int mf = 0; mf < 4; ++mf)
#pragma unroll
      for (int e = 0; e < 4; ++e) {
        float t2 = s[mf][e];
        t2 += __shfl_xor(t2, 1);
        t2 += __shfl_xor(t2, 2);
        t2 += __shfl_xor(t2, 4);
        t2 += __shfl_xor(t2, 8);
        s[mf][e] = t2;
      }
    if (lj == 0) {
#pragma unroll
      for (int mf = 0; mf < 4; ++mf)
#pragma unroll
        for (int e = 0; e < 4; ++e) red[wn][wm][mf][lg][e] = s[mf][e];
    }
    __syncthreads();
    ushort* out = reinterpret_cast<ushort*>(out1);
#pragma unroll
    for (int mf = 0; mf < 4; ++mf)
#pragma unroll
      for (int e = 0; e < 4; ++e) {
        float t2 = red[0][wm][mf][lg][e] + red[1][wm][mf][lg][e];
        float inv = 1.0f / fmaxf(sqrtf(t2), 1e-12f);
        int row = r0 + wm * 64 + mf * 16 + lg * 4 + e;
        if (row < N_NODES) {
#pragma unroll
          for (int f = 0; f < 8; ++f)
            out[(size_t)row * 256 + wn * 128 + f * 16 + lj] = f2bf(acc[mf][f][e] * inv);
        }
      }
  }
}

// ---------------- launch ----------------
extern "C" void kernel_launch(void* const* d_in, const int* in_sizes, int n_in,
                              void* d_out, int out_size, void* d_ws, size_t ws_size,
                              hipStream_t stream) {
  const float* x   = (const float*)d_in[0];
  const int*   src = (const int*)d_in[1];
  const int*   dst = (const int*)d_in[2];
  const float* Ws0 = (const float*)d_in[3];
  const float* Wn0 = (const float*)d_in[4];
  const float* b0  = (const float*)d_in[5];
  const float* Ws1 = (const float*)d_in[6];
  const float* Wn1 = (const float*)d_in[7];
  const float* b1  = (const float*)d_in[8];
  const float* Ws2 = (const float*)d_in[9];
  const float* Wn2 = (const float*)d_in[10];
  const float* b2  = (const float*)d_in[11];

  uintptr_t p = ((uintptr_t)d_ws + 255) & ~(uintptr_t)255;
  auto carve = [&](size_t bytes) {
    void* r = (void*)p;
    p += (bytes + 255) & ~(size_t)255;
    return r;
  };
  ushort* h0   = (ushort*)carve((size_t)N_NODES * DIM_IN * 2);
  ushort* Y0   = (ushort*)carve((size_t)N_NODES * DIM_H * 2);  // also reused as agg buffer
  ushort* S0   = (ushort*)carve((size_t)N_NODES * DIM_H * 2);
  ushort* h1   = (ushort*)carve((size_t)N_NODES * DIM_H * 2);
  ushort* h2   = (ushort*)carve((size_t)N_NODES * DIM_H * 2);
  ushort* Ws0p = (ushort*)carve((size_t)DIM_IN * 256 * 2);
  ushort* Wn0p = (ushort*)carve((size_t)DIM_IN * 256 * 2);
  ushort* Ws1p = (ushort*)carve((size_t)DIM_H * 256 * 2);
  ushort* Wn1p = (ushort*)carve((size_t)DIM_H * 256 * 2);
  ushort* Ws2p = (ushort*)carve((size_t)DIM_H * 256 * 2);
  ushort* Wn2p = (ushort*)carve((size_t)DIM_H * 256 * 2);
  int* deg    = (int*)carve((size_t)N_NODES * 4);
  int* rowptr = (int*)carve((size_t)N_NODES * 4);
  int* cursor = (int*)carve((size_t)N_NODES * 4);
  int* stmp   = (int*)carve((size_t)N_NODES * 4);
  int* bsum   = (int*)carve(256 * 4);
  int* csr    = (int*)carve((size_t)N_EDGES * 4);

  hipMemsetAsync(deg, 0, (size_t)N_NODES * 4, stream);

  {
    int n4 = N_NODES * DIM_IN / 4;
    log1p_kernel<<<(n4 + 255) / 256, 256, 0, stream>>>(x, h0, n4);
  }
  const int scanBlocks = (N_NODES + 255) / 256;  // 196
  hist_kernel<<<(N_EDGES + 255) / 256, 256, 0, stream>>>(dst, deg, N_EDGES);
  scan1_kernel<<<scanBlocks, 256, 0, stream>>>(deg, stmp, bsum);
  scan2_kernel<<<1, 256, 0, stream>>>(bsum, scanBlocks);
  scan3_kernel<<<scanBlocks, 256, 0, stream>>>(stmp, bsum, rowptr, cursor);
  fill_kernel<<<(N_EDGES + 255) / 256, 256, 0, stream>>>(src, dst, cursor, csr, N_EDGES);

  {
    int tot = 2 * DIM_IN * 256 + 4 * DIM_H * 256;
    pack_all_kernel<<<(tot + 255) / 256, 256, 0, stream>>>(Ws0, Wn0, Ws1, Wn1, Ws2, Wn2,
                                                           Ws0p, Wn0p, Ws1p, Wn1p, Ws2p, Wn2p);
  }

  const int aggBlocks  = (N_NODES + 7) / 8;
  const int gemmBlocks = (N_NODES + 127) / 128;

  // layer 0 (linearity trick): S0 = h0@Ws0+b0, Y0 = h0@Wn0; then fused gather+epilogue
  gemm_kernel<DIM_IN, 2><<<gemmBlocks, 256, 0, stream>>>(h0, h0, Ws0p, Wn0p, b0, S0, Y0);
  agg_fused_kernel<<<aggBlocks, 256, 0, stream>>>(Y0, S0, rowptr, deg, csr, h1);
  // layer 1
  agg_kernel<<<aggBlocks, 256, 0, stream>>>(h1, rowptr, deg, csr, Y0);
  gemm_kernel<DIM_H, 0><<<gemmBlocks, 256, 0, stream>>>(h1, Y0, Ws1p, Wn1p, b1, h2, nullptr);
  // layer 2
  agg_kernel<<<aggBlocks, 256, 0, stream>>>(h2, rowptr, deg, csr, Y0);
  gemm_kernel<DIM_H, 1><<<gemmBlocks, 256, 0, stream>>>(h2, Y0, Ws2p, Wn2p, b2, d_out, nullptr);
}

// Round 5
// 375.641 us; speedup vs baseline: 2.1408x; 1.0885x over previous
//
#include <hip/hip_runtime.h>
#include <hip/hip_bf16.h>

#define N_NODES 50000
#define N_EDGES 800000
#define DIM_IN  384
#define DIM_H   256

typedef __bf16 bf16x8 __attribute__((ext_vector_type(8)));
typedef float  f32x4  __attribute__((ext_vector_type(4)));

static __device__ __forceinline__ ushort f2bf(float f) {
  uint u = __float_as_uint(f);
  u += 0x7fffu + ((u >> 16) & 1u);
  return (ushort)(u >> 16);
}
static __device__ __forceinline__ float bf_lo(uint u) { return __uint_as_float(u << 16); }
static __device__ __forceinline__ float bf_hi(uint u) { return __uint_as_float(u & 0xffff0000u); }

typedef const __attribute__((address_space(1))) void* gas_p;
typedef __attribute__((address_space(3))) void* las_p;
static __device__ __forceinline__ void gload16(const void* g, void* l) {
  __builtin_amdgcn_global_load_lds((gas_p)g, (las_p)l, 16, 0, 0);
}

// ---------------- h0 = log1p(x), f32 -> bf16 ----------------
__global__ void log1p_kernel(const float* __restrict__ x, ushort* __restrict__ h, int n4) {
  int i = blockIdx.x * 256 + threadIdx.x;
  if (i >= n4) return;
  float4 v = reinterpret_cast<const float4*>(x)[i];
  ushort4 o;
  o.x = f2bf(log1pf(v.x));
  o.y = f2bf(log1pf(v.y));
  o.z = f2bf(log1pf(v.z));
  o.w = f2bf(log1pf(v.w));
  reinterpret_cast<ushort4*>(h)[i] = o;
}

// ---------------- CSR build ----------------
__global__ void hist_kernel(const int* __restrict__ dst, int* __restrict__ deg, int e) {
  int i = blockIdx.x * 256 + threadIdx.x;
  if (i < e) atomicAdd(&deg[dst[i]], 1);
}

__global__ void scan1_kernel(const int* __restrict__ deg, int* __restrict__ tmp,
                             int* __restrict__ bsum) {
  __shared__ int buf[256];
  int t = threadIdx.x, i = blockIdx.x * 256 + t;
  int v = (i < N_NODES) ? deg[i] : 0;
  buf[t] = v;
  __syncthreads();
  int x = v;
#pragma unroll
  for (int off = 1; off < 256; off <<= 1) {
    int y = (t >= off) ? buf[t - off] : 0;
    __syncthreads();
    x += y;
    buf[t] = x;
    __syncthreads();
  }
  if (i < N_NODES) tmp[i] = x - v;
  if (t == 255) bsum[blockIdx.x] = x;
}

__global__ void scan2_kernel(int* __restrict__ bsum, int nb) {
  __shared__ int buf[256];
  int t = threadIdx.x;
  int v = (t < nb) ? bsum[t] : 0;
  buf[t] = v;
  __syncthreads();
  int x = v;
#pragma unroll
  for (int off = 1; off < 256; off <<= 1) {
    int y = (t >= off) ? buf[t - off] : 0;
    __syncthreads();
    x += y;
    buf[t] = x;
    __syncthreads();
  }
  if (t < nb) bsum[t] = x - v;
}

__global__ void scan3_kernel(const int* __restrict__ tmp, const int* __restrict__ bsum,
                             int* __restrict__ rowptr, int* __restrict__ cursor) {
  int i = blockIdx.x * 256 + threadIdx.x;
  if (i >= N_NODES) return;
  int r = tmp[i] + bsum[i >> 8];
  rowptr[i] = r;
  cursor[i] = r;
}

__global__ void fill_kernel(const int* __restrict__ src, const int* __restrict__ dst,
                            int* __restrict__ cursor, int* __restrict__ csr, int e) {
  int i = blockIdx.x * 256 + threadIdx.x;
  if (i >= e) return;
  int d = dst[i];
  int p = atomicAdd(&cursor[d], 1);
  csr[p] = src[i];
}

// ---------------- weight prepack ----------------
// position permutation on 256-dim: p = wn*128 + lj*8 + f  <->  logical c = wn*128 + f*16 + lj
static __device__ __forceinline__ int permc(int p) {
  return ((p >> 7) << 7) + ((p & 7) << 4) + ((p >> 3) & 15);
}
// out[(kc*256 + col)*32 + kgs*8 + e] = bf16(W[krow(k)*256 + col]), kgd = kgs ^ ((col>>1)&3)
static __device__ __forceinline__ void pack_one(const float* W, ushort* out, int local, bool perm) {
  int k = local >> 8, col = local & 255;
  int kc = k >> 5, kgd = (k >> 3) & 3, e = k & 7;
  int kgs = kgd ^ ((col >> 1) & 3);
  int krow = perm ? permc(k) : k;
  out[((size_t)kc * 256 + col) * 32 + kgs * 8 + e] = f2bf(W[krow * 256 + col]);
}

__global__ void pack_all_kernel(const float* W0s, const float* W0n, const float* W1s,
                                const float* W1n, const float* W2s, const float* W2n,
                                ushort* o0s, ushort* o0n, ushort* o1s, ushort* o1n,
                                ushort* o2s, ushort* o2n) {
  int idx = blockIdx.x * 256 + threadIdx.x;
  const int SZ0 = DIM_IN * 256;
  const int SZ1 = DIM_H * 256;
  if (idx < SZ0) pack_one(W0s, o0s, idx, false);
  else if (idx < 2 * SZ0) pack_one(W0n, o0n, idx - SZ0, false);
  else {
    int j = idx - 2 * SZ0;
    int w = j / SZ1, local = j - w * SZ1;
    if (w == 0) pack_one(W1s, o1s, local, true);
    else if (w == 1) pack_one(W1n, o1n, local, true);
    else if (w == 2) pack_one(W2s, o2s, local, true);
    else if (w == 3) pack_one(W2n, o2n, local, true);
  }
}

// ---------------- dual GEMM: S = A@Ws + b (bf16 or f32), Y = int8-quant(A@Wn) ----------------
// block 128 rows x 256 cols, 4 waves (wm,wn) of 64x128, LDS double-buffered, swizzled.
// Outputs stored in POSITION layout p = wn*128 + lj*8 + f (contiguous per-thread stores).
template <int K, bool SF32>
__global__ __launch_bounds__(256, 2) void gemm_dual_kernel(const ushort* __restrict__ A,
                                                           const ushort* __restrict__ Bs,
                                                           const ushort* __restrict__ Bn,
                                                           const float* __restrict__ bias,
                                                           void* __restrict__ Sout,
                                                           unsigned char* __restrict__ Yq,
                                                           float* __restrict__ scales) {
  constexpr int KC = K / 32;
  constexpr int NT = 2 * KC;
  __shared__ ushort Al[2][4096];
  __shared__ ushort Bl[2][8192];
  __shared__ float red[2][2][4][4][4];   // [wn][wm][mf][lg][e]

  const int tid = threadIdx.x;
  const int wv = tid >> 6, lane = tid & 63, lj = lane & 15, lg = lane >> 4;
  const int wm = wv >> 1, wn = wv & 1;
  const int r0 = blockIdx.x * 128;

  int grow[2], akgd[2];
#pragma unroll
  for (int j = 0; j < 2; ++j) {
    int d = tid + j * 256;
    int row = d >> 2, kgs = d & 3;
    akgd[j] = kgs ^ ((row >> 1) & 3);
    int r = r0 + row;
    grow[j] = r < N_NODES ? r : N_NODES - 1;
  }

  int aoff[4], boff[8];
#pragma unroll
  for (int mf = 0; mf < 4; ++mf) {
    int row = wm * 64 + mf * 16 + lj;
    aoff[mf] = row * 32 + (lg ^ ((row >> 1) & 3)) * 8;
  }
#pragma unroll
  for (int f = 0; f < 8; ++f) {
    int col = wn * 128 + f * 16 + lj;
    boff[f] = col * 32 + (lg ^ ((col >> 1) & 3)) * 8;
  }

  auto stage = [&](int t, int bb) {
    int p = t >= KC;
    int kc = t - p * KC;
    const ushort* Bp = p ? Bn : Bs;
#pragma unroll
    for (int j = 0; j < 2; ++j)
      gload16(A + (size_t)grow[j] * K + kc * 32 + akgd[j] * 8,
              (char*)&Al[bb][0] + j * 4096 + wv * 1024);
#pragma unroll
    for (int j = 0; j < 4; ++j)
      gload16(Bp + (size_t)kc * 8192 + (tid + j * 256) * 8,
              (char*)&Bl[bb][0] + j * 4096 + wv * 1024);
  };

  float bvv[8];
#pragma unroll
  for (int f = 0; f < 8; ++f) bvv[f] = bias[wn * 128 + f * 16 + lj];

  f32x4 acc[4][8];
#pragma unroll
  for (int mf = 0; mf < 4; ++mf)
#pragma unroll
    for (int f = 0; f < 8; ++f) acc[mf][f] = (f32x4){0.f, 0.f, 0.f, 0.f};

  stage(0, 0);
  __syncthreads();
  int b = 0;
  for (int t = 0; t < NT; ++t) {
    if (t + 1 < NT) stage(t + 1, b ^ 1);
    bf16x8 av[4], bv[8];
#pragma unroll
    for (int mf = 0; mf < 4; ++mf)
      av[mf] = *reinterpret_cast<const bf16x8*>(&Al[b][aoff[mf]]);
#pragma unroll
    for (int f = 0; f < 8; ++f)
      bv[f] = *reinterpret_cast<const bf16x8*>(&Bl[b][boff[f]]);
#pragma unroll
    for (int mf = 0; mf < 4; ++mf)
#pragma unroll
      for (int f = 0; f < 8; ++f)
        acc[mf][f] = __builtin_amdgcn_mfma_f32_16x16x32_bf16(av[mf], bv[f], acc[mf][f], 0, 0, 0);
    if (t == KC - 1) {
      // self phase done: write S = acc + bias in position layout, reset acc
#pragma unroll
      for (int mf = 0; mf < 4; ++mf)
#pragma unroll
        for (int e = 0; e < 4; ++e) {
          int row = r0 + wm * 64 + mf * 16 + lg * 4 + e;
          if (row < N_NODES) {
            if constexpr (SF32) {
              float* pS = (float*)Sout + (size_t)row * 256 + wn * 128 + lj * 8;
              float4 v0 = {acc[mf][0][e] + bvv[0], acc[mf][1][e] + bvv[1],
                           acc[mf][2][e] + bvv[2], acc[mf][3][e] + bvv[3]};
              float4 v1 = {acc[mf][4][e] + bvv[4], acc[mf][5][e] + bvv[5],
                           acc[mf][6][e] + bvv[6], acc[mf][7][e] + bvv[7]};
              *reinterpret_cast<float4*>(pS) = v0;
              *reinterpret_cast<float4*>(pS + 4) = v1;
            } else {
              ushort* pS = (ushort*)Sout + (size_t)row * 256 + wn * 128 + lj * 8;
              uint4 o;
              o.x = (uint)f2bf(acc[mf][0][e] + bvv[0]) | ((uint)f2bf(acc[mf][1][e] + bvv[1]) << 16);
              o.y = (uint)f2bf(acc[mf][2][e] + bvv[2]) | ((uint)f2bf(acc[mf][3][e] + bvv[3]) << 16);
              o.z = (uint)f2bf(acc[mf][4][e] + bvv[4]) | ((uint)f2bf(acc[mf][5][e] + bvv[5]) << 16);
              o.w = (uint)f2bf(acc[mf][6][e] + bvv[6]) | ((uint)f2bf(acc[mf][7][e] + bvv[7]) << 16);
              *reinterpret_cast<uint4*>(pS) = o;
            }
          }
        }
#pragma unroll
      for (int mf = 0; mf < 4; ++mf)
#pragma unroll
        for (int f = 0; f < 8; ++f) acc[mf][f] = (f32x4){0.f, 0.f, 0.f, 0.f};
    }
    __syncthreads();
    b ^= 1;
  }

  // ----- Y epilogue: per-row absmax -> int8 quant (position layout) -----
  float rmax[4][4];
#pragma unroll
  for (int mf = 0; mf < 4; ++mf)
#pragma unroll
    for (int e = 0; e < 4; ++e) {
      float m = 0.f;
#pragma unroll
      for (int f = 0; f < 8; ++f) m = fmaxf(m, fabsf(acc[mf][f][e]));
      rmax[mf][e] = m;
    }
#pragma unroll
  for (int mf = 0; mf < 4; ++mf)
#pragma unroll
    for (int e = 0; e < 4; ++e) {
      float m = rmax[mf][e];
      m = fmaxf(m, __shfl_xor(m, 1));
      m = fmaxf(m, __shfl_xor(m, 2));
      m = fmaxf(m, __shfl_xor(m, 4));
      m = fmaxf(m, __shfl_xor(m, 8));
      rmax[mf][e] = m;
    }
  if (lj == 0) {
#pragma unroll
    for (int mf = 0; mf < 4; ++mf)
#pragma unroll
      for (int e = 0; e < 4; ++e) red[wn][wm][mf][lg][e] = rmax[mf][e];
  }
  __syncthreads();
#pragma unroll
  for (int mf = 0; mf < 4; ++mf)
#pragma unroll
    for (int e = 0; e < 4; ++e) {
      float m = fmaxf(fmaxf(red[0][wm][mf][lg][e], red[1][wm][mf][lg][e]), 1e-30f);
      float inv_s = 127.0f / m;
      int row = r0 + wm * 64 + mf * 16 + lg * 4 + e;
      if (row < N_NODES) {
        uint lo = 0, hi = 0;
#pragma unroll
        for (int f = 0; f < 4; ++f) {
          int q = (int)rintf(acc[mf][f][e] * inv_s) + 128;
          q = max(0, min(255, q));
          lo |= (uint)q << (8 * f);
        }
#pragma unroll
        for (int f = 4; f < 8; ++f) {
          int q = (int)rintf(acc[mf][f][e] * inv_s) + 128;
          q = max(0, min(255, q));
          hi |= (uint)q << (8 * (f - 4));
        }
        *reinterpret_cast<uint2*>(Yq + (size_t)row * 256 + wn * 128 + lj * 8) = make_uint2(lo, hi);
        if (wn == 0 && lj == 0) scales[row] = m * (1.0f / 127.0f);
      }
    }
}

// ---------------- gather: out = epilogue(S + mean(dequant(Yq[src]))) ----------------
// half-wave (32 lanes) per node; 8 int8 cols per lane (position layout).
// FINAL=false: out bf16 l2norm(relu(.)) in position layout.
// FINAL=true:  out f32 in LOGICAL layout (d_out).
template <bool FINAL>
__global__ __launch_bounds__(256) void gather_kernel(const unsigned char* __restrict__ Yq,
                                                     const float* __restrict__ scales,
                                                     const void* __restrict__ Sin,
                                                     const int* __restrict__ rowptr,
                                                     const int* __restrict__ deg,
                                                     const int* __restrict__ csr,
                                                     void* __restrict__ outv) {
  int node = blockIdx.x * 8 + (threadIdx.x >> 5);
  if (node >= N_NODES) return;
  int hl = threadIdx.x & 31;
  int start = rowptr[node];
  int d = deg[node];
  float acc[8];
#pragma unroll
  for (int i = 0; i < 8; ++i) acc[i] = 0.0f;
  float stot = 0.f;

  auto ub = [](uint u, int j) { return (float)((u >> (8 * j)) & 0xffu); };
  int e = 0;
  for (; e + 4 <= d; e += 4) {
    int s0 = csr[start + e], s1 = csr[start + e + 1];
    int s2 = csr[start + e + 2], s3 = csr[start + e + 3];
    float c0 = scales[s0], c1 = scales[s1], c2 = scales[s2], c3 = scales[s3];
    uint2 q0 = *reinterpret_cast<const uint2*>(Yq + (size_t)s0 * 256 + hl * 8);
    uint2 q1 = *reinterpret_cast<const uint2*>(Yq + (size_t)s1 * 256 + hl * 8);
    uint2 q2 = *reinterpret_cast<const uint2*>(Yq + (size_t)s2 * 256 + hl * 8);
    uint2 q3 = *reinterpret_cast<const uint2*>(Yq + (size_t)s3 * 256 + hl * 8);
    stot += c0 + c1 + c2 + c3;
#pragma unroll
    for (int j = 0; j < 4; ++j) {
      acc[j]     += c0 * ub(q0.x, j) + c1 * ub(q1.x, j) + c2 * ub(q2.x, j) + c3 * ub(q3.x, j);
      acc[4 + j] += c0 * ub(q0.y, j) + c1 * ub(q1.y, j) + c2 * ub(q2.y, j) + c3 * ub(q3.y, j);
    }
  }
  for (; e < d; ++e) {
    int s = csr[start + e];
    float c = scales[s];
    uint2 q = *reinterpret_cast<const uint2*>(Yq + (size_t)s * 256 + hl * 8);
    stot += c;
#pragma unroll
    for (int j = 0; j < 4; ++j) {
      acc[j]     += c * ub(q.x, j);
      acc[4 + j] += c * ub(q.y, j);
    }
  }

  float invd = 1.0f / fmaxf((float)d, 1.0f);
  float nb[8];
#pragma unroll
  for (int j = 0; j < 8; ++j) nb[j] = (acc[j] - 128.0f * stot) * invd;

  if constexpr (FINAL) {
    const float* S = (const float*)Sin + (size_t)node * 256 + hl * 8;
    float4 s0 = *reinterpret_cast<const float4*>(S);
    float4 s1 = *reinterpret_cast<const float4*>(S + 4);
    float sv[8] = {s0.x, s0.y, s0.z, s0.w, s1.x, s1.y, s1.z, s1.w};
    float* out = (float*)outv + (size_t)node * 256 + (hl >> 4) * 128 + (hl & 15);
#pragma unroll
    for (int f = 0; f < 8; ++f) out[f * 16] = nb[f] + sv[f];
  } else {
    const ushort* S = (const ushort*)Sin + (size_t)node * 256 + hl * 8;
    uint4 sv = *reinterpret_cast<const uint4*>(S);
    uint su[4] = {sv.x, sv.y, sv.z, sv.w};
    float v[8];
    float ssq = 0.f;
#pragma unroll
    for (int i = 0; i < 4; ++i) {
      float a = fmaxf(nb[2 * i] + bf_lo(su[i]), 0.0f);
      float b = fmaxf(nb[2 * i + 1] + bf_hi(su[i]), 0.0f);
      v[2 * i] = a; v[2 * i + 1] = b;
      ssq += a * a + b * b;
    }
    ssq += __shfl_xor(ssq, 1);
    ssq += __shfl_xor(ssq, 2);
    ssq += __shfl_xor(ssq, 4);
    ssq += __shfl_xor(ssq, 8);
    ssq += __shfl_xor(ssq, 16);
    float rn = 1.0f / fmaxf(sqrtf(ssq), 1e-12f);
    uint o[4];
#pragma unroll
    for (int i = 0; i < 4; ++i) {
      uint lo = f2bf(v[2 * i] * rn);
      uint hi = f2bf(v[2 * i + 1] * rn);
      o[i] = lo | (hi << 16);
    }
    *reinterpret_cast<uint4*>((ushort*)outv + (size_t)node * 256 + hl * 8) =
        make_uint4(o[0], o[1], o[2], o[3]);
  }
}

// ---------------- launch ----------------
extern "C" void kernel_launch(void* const* d_in, const int* in_sizes, int n_in,
                              void* d_out, int out_size, void* d_ws, size_t ws_size,
                              hipStream_t stream) {
  const float* x   = (const float*)d_in[0];
  const int*   src = (const int*)d_in[1];
  const int*   dst = (const int*)d_in[2];
  const float* Ws0 = (const float*)d_in[3];
  const float* Wn0 = (const float*)d_in[4];
  const float* b0  = (const float*)d_in[5];
  const float* Ws1 = (const float*)d_in[6];
  const float* Wn1 = (const float*)d_in[7];
  const float* b1  = (const float*)d_in[8];
  const float* Ws2 = (const float*)d_in[9];
  const float* Wn2 = (const float*)d_in[10];
  const float* b2  = (const float*)d_in[11];

  uintptr_t p = ((uintptr_t)d_ws + 255) & ~(uintptr_t)255;
  auto carve = [&](size_t bytes) {
    void* r = (void*)p;
    p += (bytes + 255) & ~(size_t)255;
    return r;
  };
  // region A: h0 (K=384 bf16) ; later h2 (K=256 bf16) at same base
  ushort* h0 = (ushort*)carve((size_t)N_NODES * DIM_IN * 2);
  ushort* h2 = h0;
  // region B: [S_mid bf16 25.6MB][h1 bf16 25.6MB] ; later S2f f32 (51.2MB whole)
  ushort* S_mid = (ushort*)carve((size_t)N_NODES * DIM_H * 2 * 2);
  ushort* h1 = S_mid + (size_t)N_NODES * DIM_H;
  float*  S2f = (float*)S_mid;
  unsigned char* Yq = (unsigned char*)carve((size_t)N_NODES * 256);
  float* scales = (float*)carve((size_t)N_NODES * 4);
  ushort* Ws0p = (ushort*)carve((size_t)DIM_IN * 256 * 2);
  ushort* Wn0p = (ushort*)carve((size_t)DIM_IN * 256 * 2);
  ushort* Ws1p = (ushort*)carve((size_t)DIM_H * 256 * 2);
  ushort* Wn1p = (ushort*)carve((size_t)DIM_H * 256 * 2);
  ushort* Ws2p = (ushort*)carve((size_t)DIM_H * 256 * 2);
  ushort* Wn2p = (ushort*)carve((size_t)DIM_H * 256 * 2);
  int* deg    = (int*)carve((size_t)N_NODES * 4);
  int* rowptr = (int*)carve((size_t)N_NODES * 4);
  int* cursor = (int*)carve((size_t)N_NODES * 4);
  int* stmp   = (int*)carve((size_t)N_NODES * 4);
  int* bsum   = (int*)carve(256 * 4);
  int* csr    = (int*)carve((size_t)N_EDGES * 4);

  hipMemsetAsync(deg, 0, (size_t)N_NODES * 4, stream);

  {
    int n4 = N_NODES * DIM_IN / 4;
    log1p_kernel<<<(n4 + 255) / 256, 256, 0, stream>>>(x, h0, n4);
  }
  const int scanBlocks = (N_NODES + 255) / 256;
  hist_kernel<<<(N_EDGES + 255) / 256, 256, 0, stream>>>(dst, deg, N_EDGES);
  scan1_kernel<<<scanBlocks, 256, 0, stream>>>(deg, stmp, bsum);
  scan2_kernel<<<1, 256, 0, stream>>>(bsum, scanBlocks);
  scan3_kernel<<<scanBlocks, 256, 0, stream>>>(stmp, bsum, rowptr, cursor);
  fill_kernel<<<(N_EDGES + 255) / 256, 256, 0, stream>>>(src, dst, cursor, csr, N_EDGES);

  {
    int tot = 2 * DIM_IN * 256 + 4 * DIM_H * 256;
    pack_all_kernel<<<(tot + 255) / 256, 256, 0, stream>>>(Ws0, Wn0, Ws1, Wn1, Ws2, Wn2,
                                                           Ws0p, Wn0p, Ws1p, Wn1p, Ws2p, Wn2p);
  }

  const int gatherBlocks = (N_NODES + 7) / 8;
  const int gemmBlocks   = (N_NODES + 127) / 128;

  // layer 0: S0 = h0@Ws0+b0 (bf16), Y0 = q8(h0@Wn0); h1 = l2norm(relu(S0 + mean(Y0[src])))
  gemm_dual_kernel<DIM_IN, false><<<gemmBlocks, 256, 0, stream>>>(h0, Ws0p, Wn0p, b0, S_mid, Yq, scales);
  gather_kernel<false><<<gatherBlocks, 256, 0, stream>>>(Yq, scales, S_mid, rowptr, deg, csr, h1);
  // layer 1
  gemm_dual_kernel<DIM_H, false><<<gemmBlocks, 256, 0, stream>>>(h1, Ws1p, Wn1p, b1, S_mid, Yq, scales);
  gather_kernel<false><<<gatherBlocks, 256, 0, stream>>>(Yq, scales, S_mid, rowptr, deg, csr, h2);
  // layer 2 (final): S2 f32, out = S2 + mean(Y2[src]) in logical layout
  gemm_dual_kernel<DIM_H, true><<<gemmBlocks, 256, 0, stream>>>(h2, Ws2p, Wn2p, b2, S2f, Yq, scales);
  gather_kernel<true><<<gatherBlocks, 256, 0, stream>>>(Yq, scales, S2f, rowptr, deg, csr, d_out);
}

// Round 6
// 330.715 us; speedup vs baseline: 2.4316x; 1.1358x over previous
//
#include <hip/hip_runtime.h>
#include <hip/hip_bf16.h>

#define N_NODES 50000
#define N_EDGES 800000
#define DIM_IN  384
#define DIM_H   256

typedef __bf16 bf16x8 __attribute__((ext_vector_type(8)));
typedef float  f32x4  __attribute__((ext_vector_type(4)));

static __device__ __forceinline__ ushort f2bf(float f) {
  uint u = __float_as_uint(f);
  u += 0x7fffu + ((u >> 16) & 1u);
  return (ushort)(u >> 16);
}
static __device__ __forceinline__ float bf_lo(uint u) { return __uint_as_float(u << 16); }
static __device__ __forceinline__ float bf_hi(uint u) { return __uint_as_float(u & 0xffff0000u); }

typedef const __attribute__((address_space(1))) void* gas_p;
typedef __attribute__((address_space(3))) void* las_p;
static __device__ __forceinline__ void gload16(const void* g, void* l) {
  __builtin_amdgcn_global_load_lds((gas_p)g, (las_p)l, 16, 0, 0);
}

// fast log1p for x in [0, 10], output destined for bf16 (0.4% rel precision)
static __device__ __forceinline__ float log1p_fast(float x) {
  return __logf(1.0f + x);   // v_log_f32 + mul
}

// ---------------- fused: h0 = log1p(x) -> bf16  ||  deg histogram ----------------
#define L1_BLOCKS ((N_NODES * DIM_IN / 4 + 255) / 256)   // 18750
#define HIST_BLOCKS ((N_EDGES + 255) / 256)              // 3125

__global__ void log1p_hist_kernel(const float* __restrict__ x, ushort* __restrict__ h,
                                  const int* __restrict__ dst, int* __restrict__ deg) {
  int bid = blockIdx.x;
  if (bid < L1_BLOCKS) {
    int i = bid * 256 + threadIdx.x;
    if (i >= N_NODES * DIM_IN / 4) return;
    float4 v = reinterpret_cast<const float4*>(x)[i];
    ushort4 o;
    o.x = f2bf(log1p_fast(v.x));
    o.y = f2bf(log1p_fast(v.y));
    o.z = f2bf(log1p_fast(v.z));
    o.w = f2bf(log1p_fast(v.w));
    reinterpret_cast<ushort4*>(h)[i] = o;
  } else {
    int i = (bid - L1_BLOCKS) * 256 + threadIdx.x;
    if (i < N_EDGES) atomicAdd(&deg[dst[i]], 1);
  }
}

// ---------------- hierarchical scan ----------------
__global__ void scan1_kernel(const int* __restrict__ deg, int* __restrict__ tmp,
                             int* __restrict__ bsum) {
  __shared__ int buf[256];
  int t = threadIdx.x, i = blockIdx.x * 256 + t;
  int v = (i < N_NODES) ? deg[i] : 0;
  buf[t] = v;
  __syncthreads();
  int x = v;
#pragma unroll
  for (int off = 1; off < 256; off <<= 1) {
    int y = (t >= off) ? buf[t - off] : 0;
    __syncthreads();
    x += y;
    buf[t] = x;
    __syncthreads();
  }
  if (i < N_NODES) tmp[i] = x - v;
  if (t == 255) bsum[blockIdx.x] = x;
}

__global__ void scan2_kernel(int* __restrict__ bsum, int nb) {
  __shared__ int buf[256];
  int t = threadIdx.x;
  int v = (t < nb) ? bsum[t] : 0;
  buf[t] = v;
  __syncthreads();
  int x = v;
#pragma unroll
  for (int off = 1; off < 256; off <<= 1) {
    int y = (t >= off) ? buf[t - off] : 0;
    __syncthreads();
    x += y;
    buf[t] = x;
    __syncthreads();
  }
  if (t < nb) bsum[t] = x - v;
}

__global__ void scan3_kernel(const int* __restrict__ tmp, const int* __restrict__ bsum,
                             int* __restrict__ rowptr, int* __restrict__ cursor) {
  int i = blockIdx.x * 256 + threadIdx.x;
  if (i >= N_NODES) return;
  int r = tmp[i] + bsum[i >> 8];
  rowptr[i] = r;
  cursor[i] = r;
}

// ---------------- weight prepack helpers ----------------
static __device__ __forceinline__ int permc(int p) {
  return ((p >> 7) << 7) + ((p & 7) << 4) + ((p >> 3) & 15);
}
static __device__ __forceinline__ void pack_one(const float* W, ushort* out, int local, bool perm) {
  int k = local >> 8, col = local & 255;
  int kc = k >> 5, kgd = (k >> 3) & 3, e = k & 7;
  int kgs = kgd ^ ((col >> 1) & 3);
  int krow = perm ? permc(k) : k;
  out[((size_t)kc * 256 + col) * 32 + kgs * 8 + e] = f2bf(W[krow * 256 + col]);
}

// ---------------- fused: CSR fill (ushort payload)  ||  weight prepack ----------------
#define FILL_BLOCKS ((N_EDGES + 255) / 256)                        // 3125
#define PACK_TOT (2 * DIM_IN * 256 + 4 * DIM_H * 256)              // 458752
#define PACK_BLOCKS ((PACK_TOT + 255) / 256)                       // 1792

__global__ void fill_pack_kernel(const int* __restrict__ src, const int* __restrict__ dst,
                                 int* __restrict__ cursor, ushort* __restrict__ csr,
                                 const float* W0s, const float* W0n, const float* W1s,
                                 const float* W1n, const float* W2s, const float* W2n,
                                 ushort* o0s, ushort* o0n, ushort* o1s, ushort* o1n,
                                 ushort* o2s, ushort* o2n) {
  int bid = blockIdx.x;
  if (bid < FILL_BLOCKS) {
    int i = bid * 256 + threadIdx.x;
    if (i >= N_EDGES) return;
    int d = dst[i];
    int p = atomicAdd(&cursor[d], 1);
    csr[p] = (ushort)src[i];
  } else {
    int idx = (bid - FILL_BLOCKS) * 256 + threadIdx.x;
    const int SZ0 = DIM_IN * 256;
    const int SZ1 = DIM_H * 256;
    if (idx < SZ0) pack_one(W0s, o0s, idx, false);
    else if (idx < 2 * SZ0) pack_one(W0n, o0n, idx - SZ0, false);
    else {
      int j = idx - 2 * SZ0;
      int w = j / SZ1, local = j - w * SZ1;
      if (w == 0) pack_one(W1s, o1s, local, true);
      else if (w == 1) pack_one(W1n, o1n, local, true);
      else if (w == 2) pack_one(W2s, o2s, local, true);
      else if (w == 3) pack_one(W2n, o2n, local, true);
    }
  }
}

// ---------------- dual GEMM: S = A@Ws + b, Yq = int8(A@Wn) ----------------
template <int K, bool SF32>
__global__ __launch_bounds__(256, 2) void gemm_dual_kernel(const ushort* __restrict__ A,
                                                           const ushort* __restrict__ Bs,
                                                           const ushort* __restrict__ Bn,
                                                           const float* __restrict__ bias,
                                                           void* __restrict__ Sout,
                                                           unsigned char* __restrict__ Yq,
                                                           float* __restrict__ scales) {
  constexpr int KC = K / 32;
  constexpr int NT = 2 * KC;
  __shared__ ushort Al[2][4096];
  __shared__ ushort Bl[2][8192];
  __shared__ float red[2][2][4][4][4];

  const int tid = threadIdx.x;
  const int wv = tid >> 6, lane = tid & 63, lj = lane & 15, lg = lane >> 4;
  const int wm = wv >> 1, wn = wv & 1;
  const int r0 = blockIdx.x * 128;

  int grow[2], akgd[2];
#pragma unroll
  for (int j = 0; j < 2; ++j) {
    int d = tid + j * 256;
    int row = d >> 2, kgs = d & 3;
    akgd[j] = kgs ^ ((row >> 1) & 3);
    int r = r0 + row;
    grow[j] = r < N_NODES ? r : N_NODES - 1;
  }

  int aoff[4], boff[8];
#pragma unroll
  for (int mf = 0; mf < 4; ++mf) {
    int row = wm * 64 + mf * 16 + lj;
    aoff[mf] = row * 32 + (lg ^ ((row >> 1) & 3)) * 8;
  }
#pragma unroll
  for (int f = 0; f < 8; ++f) {
    int col = wn * 128 + f * 16 + lj;
    boff[f] = col * 32 + (lg ^ ((col >> 1) & 3)) * 8;
  }

  auto stage = [&](int t, int bb) {
    int p = t >= KC;
    int kc = t - p * KC;
    const ushort* Bp = p ? Bn : Bs;
#pragma unroll
    for (int j = 0; j < 2; ++j)
      gload16(A + (size_t)grow[j] * K + kc * 32 + akgd[j] * 8,
              (char*)&Al[bb][0] + j * 4096 + wv * 1024);
#pragma unroll
    for (int j = 0; j < 4; ++j)
      gload16(Bp + (size_t)kc * 8192 + (tid + j * 256) * 8,
              (char*)&Bl[bb][0] + j * 4096 + wv * 1024);
  };

  float bvv[8];
#pragma unroll
  for (int f = 0; f < 8; ++f) bvv[f] = bias[wn * 128 + f * 16 + lj];

  f32x4 acc[4][8];
#pragma unroll
  for (int mf = 0; mf < 4; ++mf)
#pragma unroll
    for (int f = 0; f < 8; ++f) acc[mf][f] = (f32x4){0.f, 0.f, 0.f, 0.f};

  stage(0, 0);
  __syncthreads();
  int b = 0;
  for (int t = 0; t < NT; ++t) {
    if (t + 1 < NT) stage(t + 1, b ^ 1);
    bf16x8 av[4], bv[8];
#pragma unroll
    for (int mf = 0; mf < 4; ++mf)
      av[mf] = *reinterpret_cast<const bf16x8*>(&Al[b][aoff[mf]]);
#pragma unroll
    for (int f = 0; f < 8; ++f)
      bv[f] = *reinterpret_cast<const bf16x8*>(&Bl[b][boff[f]]);
#pragma unroll
    for (int mf = 0; mf < 4; ++mf)
#pragma unroll
      for (int f = 0; f < 8; ++f)
        acc[mf][f] = __builtin_amdgcn_mfma_f32_16x16x32_bf16(av[mf], bv[f], acc[mf][f], 0, 0, 0);
    if (t == KC - 1) {
#pragma unroll
      for (int mf = 0; mf < 4; ++mf)
#pragma unroll
        for (int e = 0; e < 4; ++e) {
          int row = r0 + wm * 64 + mf * 16 + lg * 4 + e;
          if (row < N_NODES) {
            if constexpr (SF32) {
              float* pS = (float*)Sout + (size_t)row * 256 + wn * 128 + lj * 8;
              float4 v0 = {acc[mf][0][e] + bvv[0], acc[mf][1][e] + bvv[1],
                           acc[mf][2][e] + bvv[2], acc[mf][3][e] + bvv[3]};
              float4 v1 = {acc[mf][4][e] + bvv[4], acc[mf][5][e] + bvv[5],
                           acc[mf][6][e] + bvv[6], acc[mf][7][e] + bvv[7]};
              *reinterpret_cast<float4*>(pS) = v0;
              *reinterpret_cast<float4*>(pS + 4) = v1;
            } else {
              ushort* pS = (ushort*)Sout + (size_t)row * 256 + wn * 128 + lj * 8;
              uint4 o;
              o.x = (uint)f2bf(acc[mf][0][e] + bvv[0]) | ((uint)f2bf(acc[mf][1][e] + bvv[1]) << 16);
              o.y = (uint)f2bf(acc[mf][2][e] + bvv[2]) | ((uint)f2bf(acc[mf][3][e] + bvv[3]) << 16);
              o.z = (uint)f2bf(acc[mf][4][e] + bvv[4]) | ((uint)f2bf(acc[mf][5][e] + bvv[5]) << 16);
              o.w = (uint)f2bf(acc[mf][6][e] + bvv[6]) | ((uint)f2bf(acc[mf][7][e] + bvv[7]) << 16);
              *reinterpret_cast<uint4*>(pS) = o;
            }
          }
        }
#pragma unroll
      for (int mf = 0; mf < 4; ++mf)
#pragma unroll
        for (int f = 0; f < 8; ++f) acc[mf][f] = (f32x4){0.f, 0.f, 0.f, 0.f};
    }
    __syncthreads();
    b ^= 1;
  }

  float rmax[4][4];
#pragma unroll
  for (int mf = 0; mf < 4; ++mf)
#pragma unroll
    for (int e = 0; e < 4; ++e) {
      float m = 0.f;
#pragma unroll
      for (int f = 0; f < 8; ++f) m = fmaxf(m, fabsf(acc[mf][f][e]));
      rmax[mf][e] = m;
    }
#pragma unroll
  for (int mf = 0; mf < 4; ++mf)
#pragma unroll
    for (int e = 0; e < 4; ++e) {
      float m = rmax[mf][e];
      m = fmaxf(m, __shfl_xor(m, 1));
      m = fmaxf(m, __shfl_xor(m, 2));
      m = fmaxf(m, __shfl_xor(m, 4));
      m = fmaxf(m, __shfl_xor(m, 8));
      rmax[mf][e] = m;
    }
  if (lj == 0) {
#pragma unroll
    for (int mf = 0; mf < 4; ++mf)
#pragma unroll
      for (int e = 0; e < 4; ++e) red[wn][wm][mf][lg][e] = rmax[mf][e];
  }
  __syncthreads();
#pragma unroll
  for (int mf = 0; mf < 4; ++mf)
#pragma unroll
    for (int e = 0; e < 4; ++e) {
      float m = fmaxf(fmaxf(red[0][wm][mf][lg][e], red[1][wm][mf][lg][e]), 1e-30f);
      float inv_s = 127.0f / m;
      int row = r0 + wm * 64 + mf * 16 + lg * 4 + e;
      if (row < N_NODES) {
        uint lo = 0, hi = 0;
#pragma unroll
        for (int f = 0; f < 4; ++f) {
          int q = (int)rintf(acc[mf][f][e] * inv_s) + 128;
          q = max(0, min(255, q));
          lo |= (uint)q << (8 * f);
        }
#pragma unroll
        for (int f = 4; f < 8; ++f) {
          int q = (int)rintf(acc[mf][f][e] * inv_s) + 128;
          q = max(0, min(255, q));
          hi |= (uint)q << (8 * (f - 4));
        }
        *reinterpret_cast<uint2*>(Yq + (size_t)row * 256 + wn * 128 + lj * 8) = make_uint2(lo, hi);
        if (wn == 0 && lj == 0) scales[row] = m * (1.0f / 127.0f);
      }
    }
}

// ---------------- gather: out = epilogue(S + mean(dequant(Yq[src]))) ----------------
template <bool FINAL>
__global__ __launch_bounds__(256) void gather_kernel(const unsigned char* __restrict__ Yq,
                                                     const float* __restrict__ scales,
                                                     const void* __restrict__ Sin,
                                                     const int* __restrict__ rowptr,
                                                     const int* __restrict__ deg,
                                                     const ushort* __restrict__ csr,
                                                     void* __restrict__ outv) {
  int node = blockIdx.x * 8 + (threadIdx.x >> 5);
  if (node >= N_NODES) return;
  int hl = threadIdx.x & 31;
  int start = rowptr[node];
  int d = deg[node];
  float acc[8];
#pragma unroll
  for (int i = 0; i < 8; ++i) acc[i] = 0.0f;
  float stot = 0.f;

  auto ub = [](uint u, int j) { return (float)((u >> (8 * j)) & 0xffu); };
  int e = 0;
  for (; e + 4 <= d; e += 4) {
    int s0 = csr[start + e], s1 = csr[start + e + 1];
    int s2 = csr[start + e + 2], s3 = csr[start + e + 3];
    float c0 = scales[s0], c1 = scales[s1], c2 = scales[s2], c3 = scales[s3];
    uint2 q0 = *reinterpret_cast<const uint2*>(Yq + (size_t)s0 * 256 + hl * 8);
    uint2 q1 = *reinterpret_cast<const uint2*>(Yq + (size_t)s1 * 256 + hl * 8);
    uint2 q2 = *reinterpret_cast<const uint2*>(Yq + (size_t)s2 * 256 + hl * 8);
    uint2 q3 = *reinterpret_cast<const uint2*>(Yq + (size_t)s3 * 256 + hl * 8);
    stot += c0 + c1 + c2 + c3;
#pragma unroll
    for (int j = 0; j < 4; ++j) {
      acc[j]     += c0 * ub(q0.x, j) + c1 * ub(q1.x, j) + c2 * ub(q2.x, j) + c3 * ub(q3.x, j);
      acc[4 + j] += c0 * ub(q0.y, j) + c1 * ub(q1.y, j) + c2 * ub(q2.y, j) + c3 * ub(q3.y, j);
    }
  }
  for (; e < d; ++e) {
    int s = csr[start + e];
    float c = scales[s];
    uint2 q = *reinterpret_cast<const uint2*>(Yq + (size_t)s * 256 + hl * 8);
    stot += c;
#pragma unroll
    for (int j = 0; j < 4; ++j) {
      acc[j]     += c * ub(q.x, j);
      acc[4 + j] += c * ub(q.y, j);
    }
  }

  float invd = 1.0f / fmaxf((float)d, 1.0f);
  float nb[8];
#pragma unroll
  for (int j = 0; j < 8; ++j) nb[j] = (acc[j] - 128.0f * stot) * invd;

  if constexpr (FINAL) {
    const float* S = (const float*)Sin + (size_t)node * 256 + hl * 8;
    float4 s0 = *reinterpret_cast<const float4*>(S);
    float4 s1 = *reinterpret_cast<const float4*>(S + 4);
    float sv[8] = {s0.x, s0.y, s0.z, s0.w, s1.x, s1.y, s1.z, s1.w};
    float* out = (float*)outv + (size_t)node * 256 + (hl >> 4) * 128 + (hl & 15);
#pragma unroll
    for (int f = 0; f < 8; ++f) out[f * 16] = nb[f] + sv[f];
  } else {
    const ushort* S = (const ushort*)Sin + (size_t)node * 256 + hl * 8;
    uint4 sv = *reinterpret_cast<const uint4*>(S);
    uint su[4] = {sv.x, sv.y, sv.z, sv.w};
    float v[8];
    float ssq = 0.f;
#pragma unroll
    for (int i = 0; i < 4; ++i) {
      float a = fmaxf(nb[2 * i] + bf_lo(su[i]), 0.0f);
      float b = fmaxf(nb[2 * i + 1] + bf_hi(su[i]), 0.0f);
      v[2 * i] = a; v[2 * i + 1] = b;
      ssq += a * a + b * b;
    }
    ssq += __shfl_xor(ssq, 1);
    ssq += __shfl_xor(ssq, 2);
    ssq += __shfl_xor(ssq, 4);
    ssq += __shfl_xor(ssq, 8);
    ssq += __shfl_xor(ssq, 16);
    float rn = 1.0f / fmaxf(sqrtf(ssq), 1e-12f);
    uint o[4];
#pragma unroll
    for (int i = 0; i < 4; ++i) {
      uint lo = f2bf(v[2 * i] * rn);
      uint hi = f2bf(v[2 * i + 1] * rn);
      o[i] = lo | (hi << 16);
    }
    *reinterpret_cast<uint4*>((ushort*)outv + (size_t)node * 256 + hl * 8) =
        make_uint4(o[0], o[1], o[2], o[3]);
  }
}

// ---------------- launch ----------------
extern "C" void kernel_launch(void* const* d_in, const int* in_sizes, int n_in,
                              void* d_out, int out_size, void* d_ws, size_t ws_size,
                              hipStream_t stream) {
  const float* x   = (const float*)d_in[0];
  const int*   src = (const int*)d_in[1];
  const int*   dst = (const int*)d_in[2];
  const float* Ws0 = (const float*)d_in[3];
  const float* Wn0 = (const float*)d_in[4];
  const float* b0  = (const float*)d_in[5];
  const float* Ws1 = (const float*)d_in[6];
  const float* Wn1 = (const float*)d_in[7];
  const float* b1  = (const float*)d_in[8];
  const float* Ws2 = (const float*)d_in[9];
  const float* Wn2 = (const float*)d_in[10];
  const float* b2  = (const float*)d_in[11];

  uintptr_t p = ((uintptr_t)d_ws + 255) & ~(uintptr_t)255;
  auto carve = [&](size_t bytes) {
    void* r = (void*)p;
    p += (bytes + 255) & ~(size_t)255;
    return r;
  };
  ushort* h0 = (ushort*)carve((size_t)N_NODES * DIM_IN * 2);
  ushort* h2 = h0;
  ushort* S_mid = (ushort*)carve((size_t)N_NODES * DIM_H * 2 * 2);
  ushort* h1 = S_mid + (size_t)N_NODES * DIM_H;
  float*  S2f = (float*)S_mid;
  unsigned char* Yq = (unsigned char*)carve((size_t)N_NODES * 256);
  float* scales = (float*)carve((size_t)N_NODES * 4);
  ushort* Ws0p = (ushort*)carve((size_t)DIM_IN * 256 * 2);
  ushort* Wn0p = (ushort*)carve((size_t)DIM_IN * 256 * 2);
  ushort* Ws1p = (ushort*)carve((size_t)DIM_H * 256 * 2);
  ushort* Wn1p = (ushort*)carve((size_t)DIM_H * 256 * 2);
  ushort* Ws2p = (ushort*)carve((size_t)DIM_H * 256 * 2);
  ushort* Wn2p = (ushort*)carve((size_t)DIM_H * 256 * 2);
  int* deg    = (int*)carve((size_t)N_NODES * 4);
  int* rowptr = (int*)carve((size_t)N_NODES * 4);
  int* cursor = (int*)carve((size_t)N_NODES * 4);
  int* stmp   = (int*)carve((size_t)N_NODES * 4);
  int* bsum   = (int*)carve(256 * 4);
  ushort* csr = (ushort*)carve((size_t)N_EDGES * 2);

  hipMemsetAsync(deg, 0, (size_t)N_NODES * 4, stream);

  // fused log1p + degree histogram
  log1p_hist_kernel<<<L1_BLOCKS + HIST_BLOCKS, 256, 0, stream>>>(x, h0, dst, deg);

  const int scanBlocks = (N_NODES + 255) / 256;
  scan1_kernel<<<scanBlocks, 256, 0, stream>>>(deg, stmp, bsum);
  scan2_kernel<<<1, 256, 0, stream>>>(bsum, scanBlocks);
  scan3_kernel<<<scanBlocks, 256, 0, stream>>>(stmp, bsum, rowptr, cursor);

  // fused CSR fill + weight prepack
  fill_pack_kernel<<<FILL_BLOCKS + PACK_BLOCKS, 256, 0, stream>>>(
      src, dst, cursor, csr, Ws0, Wn0, Ws1, Wn1, Ws2, Wn2,
      Ws0p, Wn0p, Ws1p, Wn1p, Ws2p, Wn2p);

  const int gatherBlocks = (N_NODES + 7) / 8;
  const int gemmBlocks   = (N_NODES + 127) / 128;

  gemm_dual_kernel<DIM_IN, false><<<gemmBlocks, 256, 0, stream>>>(h0, Ws0p, Wn0p, b0, S_mid, Yq, scales);
  gather_kernel<false><<<gatherBlocks, 256, 0, stream>>>(Yq, scales, S_mid, rowptr, deg, csr, h1);
  gemm_dual_kernel<DIM_H, false><<<gemmBlocks, 256, 0, stream>>>(h1, Ws1p, Wn1p, b1, S_mid, Yq, scales);
  gather_kernel<false><<<gatherBlocks, 256, 0, stream>>>(Yq, scales, S_mid, rowptr, deg, csr, h2);
  gemm_dual_kernel<DIM_H, true><<<gemmBlocks, 256, 0, stream>>>(h2, Ws2p, Wn2p, b2, S2f, Yq, scales);
  gather_kernel<true><<<gatherBlocks, 256, 0, stream>>>(Yq, scales, S2f, rowptr, deg, csr, d_out);
}

// Round 7
// 297.984 us; speedup vs baseline: 2.6987x; 1.1098x over previous
//
#include <hip/hip_runtime.h>
#include <hip/hip_bf16.h>

#define N_NODES 50000
#define N_EDGES 800000
#define DIM_IN  384
#define DIM_H   256

typedef __bf16 bf16x8 __attribute__((ext_vector_type(8)));
typedef float  f32x4  __attribute__((ext_vector_type(4)));

static __device__ __forceinline__ ushort f2bf(float f) {
  uint u = __float_as_uint(f);
  u += 0x7fffu + ((u >> 16) & 1u);
  return (ushort)(u >> 16);
}
static __device__ __forceinline__ float bf_lo(uint u) { return __uint_as_float(u << 16); }
static __device__ __forceinline__ float bf_hi(uint u) { return __uint_as_float(u & 0xffff0000u); }

typedef const __attribute__((address_space(1))) void* gas_p;
typedef __attribute__((address_space(3))) void* las_p;
static __device__ __forceinline__ void gload16(const void* g, void* l) {
  __builtin_amdgcn_global_load_lds((gas_p)g, (las_p)l, 16, 0, 0);
}

// fast log1p for x in [0,10], destined for bf16
static __device__ __forceinline__ float log1p_fast(float x) {
  return __logf(1.0f + x);
}

// ---------------- weight prepack helpers ----------------
static __device__ __forceinline__ int permc(int p) {
  return ((p >> 7) << 7) + ((p & 7) << 4) + ((p >> 3) & 15);
}
static __device__ __forceinline__ void pack_one(const float* W, ushort* out, int local, bool perm) {
  int k = local >> 8, col = local & 255;
  int kc = k >> 5, kgd = (k >> 3) & 3, e = k & 7;
  int kgs = kgd ^ ((col >> 1) & 3);
  int krow = perm ? permc(k) : k;
  out[((size_t)kc * 256 + col) * 32 + kgs * 8 + e] = f2bf(W[krow * 256 + col]);
}

// ---------------- prep: striped {hist : log1p} + pack tail ----------------
#define HIST_BLOCKS 3125                       // N_EDGES/256
#define L1_BLOCKS   18750                      // N_NODES*DIM_IN/4/256
#define STRIPE1_TOT (HIST_BLOCKS * 7)          // 21875 = hist + 6x log1p
#define PACK_TOT (2 * DIM_IN * 256 + 4 * DIM_H * 256)
#define PACK_BLOCKS ((PACK_TOT + 255) / 256)   // 1792

__global__ void prep_kernel(const float* __restrict__ x, ushort* __restrict__ h,
                            const int* __restrict__ dst, int* __restrict__ deg,
                            const float* W0s, const float* W0n, const float* W1s,
                            const float* W1n, const float* W2s, const float* W2n,
                            ushort* o0s, ushort* o0n, ushort* o1s, ushort* o1n,
                            ushort* o2s, ushort* o2n) {
  int bid = blockIdx.x;
  if (bid < STRIPE1_TOT) {
    int g = bid / 7, r = bid - g * 7;
    if (r == 0) {
      int i = g * 256 + threadIdx.x;
      if (i < N_EDGES) atomicAdd(&deg[dst[i]], 1);
    } else {
      int i = (g * 6 + (r - 1)) * 256 + threadIdx.x;
      float4 v = reinterpret_cast<const float4*>(x)[i];
      ushort4 o;
      o.x = f2bf(log1p_fast(v.x));
      o.y = f2bf(log1p_fast(v.y));
      o.z = f2bf(log1p_fast(v.z));
      o.w = f2bf(log1p_fast(v.w));
      reinterpret_cast<ushort4*>(h)[i] = o;
    }
  } else {
    int idx = (bid - STRIPE1_TOT) * 256 + threadIdx.x;
    const int SZ0 = DIM_IN * 256;
    const int SZ1 = DIM_H * 256;
    if (idx < SZ0) pack_one(W0s, o0s, idx, false);
    else if (idx < 2 * SZ0) pack_one(W0n, o0n, idx - SZ0, false);
    else if (idx < PACK_TOT) {
      int j = idx - 2 * SZ0;
      int w = j / SZ1, local = j - w * SZ1;
      if (w == 0) pack_one(W1s, o1s, local, true);
      else if (w == 1) pack_one(W1n, o1n, local, true);
      else if (w == 2) pack_one(W2s, o2s, local, true);
      else pack_one(W2n, o2n, local, true);
    }
  }
}

// ---------------- hierarchical scan ----------------
__global__ void scan1_kernel(const int* __restrict__ deg, int* __restrict__ tmp,
                             int* __restrict__ bsum) {
  __shared__ int buf[256];
  int t = threadIdx.x, i = blockIdx.x * 256 + t;
  int v = (i < N_NODES) ? deg[i] : 0;
  buf[t] = v;
  __syncthreads();
  int x = v;
#pragma unroll
  for (int off = 1; off < 256; off <<= 1) {
    int y = (t >= off) ? buf[t - off] : 0;
    __syncthreads();
    x += y;
    buf[t] = x;
    __syncthreads();
  }
  if (i < N_NODES) tmp[i] = x - v;
  if (t == 255) bsum[blockIdx.x] = x;
}

__global__ void scan2_kernel(int* __restrict__ bsum, int nb) {
  __shared__ int buf[256];
  int t = threadIdx.x;
  int v = (t < nb) ? bsum[t] : 0;
  buf[t] = v;
  __syncthreads();
  int x = v;
#pragma unroll
  for (int off = 1; off < 256; off <<= 1) {
    int y = (t >= off) ? buf[t - off] : 0;
    __syncthreads();
    x += y;
    buf[t] = x;
    __syncthreads();
  }
  if (t < nb) bsum[t] = x - v;
}

__global__ void scan3_kernel(const int* __restrict__ tmp, const int* __restrict__ bsum,
                             int* __restrict__ rowptr, int* __restrict__ cursor) {
  int i = blockIdx.x * 256 + threadIdx.x;
  if (i >= N_NODES) return;
  int r = tmp[i] + bsum[i >> 8];
  rowptr[i] = r;
  cursor[i] = r;
}

// ---------------- dual GEMM body: S = bf16(A@Ws + b), Yq = int8(A@Wn) ----------------
// block 128 rows x 256 cols, 4 waves, LDS double-buffered, XOR-swizzled.
// outputs in position layout p = wn*128 + lj*8 + f.
template <int K>
static __device__ void gemm_dual_body(int blk, ushort* Al, ushort* Bl, float* red,
                                      const ushort* __restrict__ A,
                                      const ushort* __restrict__ Bs,
                                      const ushort* __restrict__ Bn,
                                      const float* __restrict__ bias,
                                      ushort* __restrict__ Sout,
                                      unsigned char* __restrict__ Yq,
                                      float* __restrict__ scales) {
  constexpr int KC = K / 32;
  constexpr int NT = 2 * KC;
  const int tid = threadIdx.x;
  const int wv = tid >> 6, lane = tid & 63, lj = lane & 15, lg = lane >> 4;
  const int wm = wv >> 1, wn = wv & 1;
  const int r0 = blk * 128;

  int grow[2], akgd[2];
#pragma unroll
  for (int j = 0; j < 2; ++j) {
    int d = tid + j * 256;
    int row = d >> 2, kgs = d & 3;
    akgd[j] = kgs ^ ((row >> 1) & 3);
    int r = r0 + row;
    grow[j] = r < N_NODES ? r : N_NODES - 1;
  }

  int aoff[4], boff[8];
#pragma unroll
  for (int mf = 0; mf < 4; ++mf) {
    int row = wm * 64 + mf * 16 + lj;
    aoff[mf] = row * 32 + (lg ^ ((row >> 1) & 3)) * 8;
  }
#pragma unroll
  for (int f = 0; f < 8; ++f) {
    int col = wn * 128 + f * 16 + lj;
    boff[f] = col * 32 + (lg ^ ((col >> 1) & 3)) * 8;
  }

  auto stage = [&](int t, int bb) {
    int p = t >= KC;
    int kc = t - p * KC;
    const ushort* Bp = p ? Bn : Bs;
#pragma unroll
    for (int j = 0; j < 2; ++j)
      gload16(A + (size_t)grow[j] * K + kc * 32 + akgd[j] * 8,
              (char*)(Al + bb * 4096) + j * 4096 + wv * 1024);
#pragma unroll
    for (int j = 0; j < 4; ++j)
      gload16(Bp + (size_t)kc * 8192 + (tid + j * 256) * 8,
              (char*)(Bl + bb * 8192) + j * 4096 + wv * 1024);
  };

  float bvv[8];
#pragma unroll
  for (int f = 0; f < 8; ++f) bvv[f] = bias[wn * 128 + f * 16 + lj];

  f32x4 acc[4][8];
#pragma unroll
  for (int mf = 0; mf < 4; ++mf)
#pragma unroll
    for (int f = 0; f < 8; ++f) acc[mf][f] = (f32x4){0.f, 0.f, 0.f, 0.f};

  stage(0, 0);
  __syncthreads();
  int b = 0;
  for (int t = 0; t < NT; ++t) {
    if (t + 1 < NT) stage(t + 1, b ^ 1);
    bf16x8 av[4], bv[8];
#pragma unroll
    for (int mf = 0; mf < 4; ++mf)
      av[mf] = *reinterpret_cast<const bf16x8*>(Al + b * 4096 + aoff[mf]);
#pragma unroll
    for (int f = 0; f < 8; ++f)
      bv[f] = *reinterpret_cast<const bf16x8*>(Bl + b * 8192 + boff[f]);
#pragma unroll
    for (int mf = 0; mf < 4; ++mf)
#pragma unroll
      for (int f = 0; f < 8; ++f)
        acc[mf][f] = __builtin_amdgcn_mfma_f32_16x16x32_bf16(av[mf], bv[f], acc[mf][f], 0, 0, 0);
    if (t == KC - 1) {
#pragma unroll
      for (int mf = 0; mf < 4; ++mf)
#pragma unroll
        for (int e = 0; e < 4; ++e) {
          int row = r0 + wm * 64 + mf * 16 + lg * 4 + e;
          if (row < N_NODES) {
            ushort* pS = Sout + (size_t)row * 256 + wn * 128 + lj * 8;
            uint4 o;
            o.x = (uint)f2bf(acc[mf][0][e] + bvv[0]) | ((uint)f2bf(acc[mf][1][e] + bvv[1]) << 16);
            o.y = (uint)f2bf(acc[mf][2][e] + bvv[2]) | ((uint)f2bf(acc[mf][3][e] + bvv[3]) << 16);
            o.z = (uint)f2bf(acc[mf][4][e] + bvv[4]) | ((uint)f2bf(acc[mf][5][e] + bvv[5]) << 16);
            o.w = (uint)f2bf(acc[mf][6][e] + bvv[6]) | ((uint)f2bf(acc[mf][7][e] + bvv[7]) << 16);
            *reinterpret_cast<uint4*>(pS) = o;
          }
        }
#pragma unroll
      for (int mf = 0; mf < 4; ++mf)
#pragma unroll
        for (int f = 0; f < 8; ++f) acc[mf][f] = (f32x4){0.f, 0.f, 0.f, 0.f};
    }
    __syncthreads();
    b ^= 1;
  }

  // Y epilogue: per-row absmax -> int8 quant
  float rmax[4][4];
#pragma unroll
  for (int mf = 0; mf < 4; ++mf)
#pragma unroll
    for (int e = 0; e < 4; ++e) {
      float m = 0.f;
#pragma unroll
      for (int f = 0; f < 8; ++f) m = fmaxf(m, fabsf(acc[mf][f][e]));
      m = fmaxf(m, __shfl_xor(m, 1));
      m = fmaxf(m, __shfl_xor(m, 2));
      m = fmaxf(m, __shfl_xor(m, 4));
      m = fmaxf(m, __shfl_xor(m, 8));
      rmax[mf][e] = m;
    }
  if (lj == 0) {
#pragma unroll
    for (int mf = 0; mf < 4; ++mf)
#pragma unroll
      for (int e = 0; e < 4; ++e)
        red[(wn * 2 + wm) * 64 + mf * 16 + lg * 4 + e] = rmax[mf][e];
  }
  __syncthreads();
#pragma unroll
  for (int mf = 0; mf < 4; ++mf)
#pragma unroll
    for (int e = 0; e < 4; ++e) {
      float m = fmaxf(fmaxf(red[(0 * 2 + wm) * 64 + mf * 16 + lg * 4 + e],
                            red[(1 * 2 + wm) * 64 + mf * 16 + lg * 4 + e]), 1e-30f);
      float inv_s = 127.0f / m;
      int row = r0 + wm * 64 + mf * 16 + lg * 4 + e;
      if (row < N_NODES) {
        uint lo = 0, hi = 0;
#pragma unroll
        for (int f = 0; f < 4; ++f) {
          int q = (int)rintf(acc[mf][f][e] * inv_s) + 128;
          q = max(0, min(255, q));
          lo |= (uint)q << (8 * f);
        }
#pragma unroll
        for (int f = 4; f < 8; ++f) {
          int q = (int)rintf(acc[mf][f][e] * inv_s) + 128;
          q = max(0, min(255, q));
          hi |= (uint)q << (8 * (f - 4));
        }
        *reinterpret_cast<uint2*>(Yq + (size_t)row * 256 + wn * 128 + lj * 8) = make_uint2(lo, hi);
        if (wn == 0 && lj == 0) scales[row] = m * (1.0f / 127.0f);
      }
    }
}

// ---------------- striped {gemm0 : CSR fill} ----------------
#define GEMM_BLOCKS ((N_NODES + 127) / 128)     // 391
#define GF_TOT (GEMM_BLOCKS * 9)                // 3519: 1 gemm + 8 fill per stripe

__global__ __launch_bounds__(256, 2) void gemm0_fill_kernel(
    const ushort* __restrict__ A, const ushort* __restrict__ Bs,
    const ushort* __restrict__ Bn, const float* __restrict__ bias,
    ushort* __restrict__ Sout, unsigned char* __restrict__ Yq, float* __restrict__ scales,
    const int* __restrict__ src, const int* __restrict__ dst,
    int* __restrict__ cursor, ushort* __restrict__ csr) {
  __shared__ ushort Al[2 * 4096];
  __shared__ ushort Bl[2 * 8192];
  __shared__ float red[256];
  int g = blockIdx.x / 9, r = blockIdx.x - g * 9;
  if (r == 0) {
    gemm_dual_body<DIM_IN>(g, Al, Bl, red, A, Bs, Bn, bias, Sout, Yq, scales);
  } else {
    int i = (g * 8 + (r - 1)) * 256 + threadIdx.x;
    if (i < N_EDGES) {
      int d = dst[i];
      int p = atomicAdd(&cursor[d], 1);
      csr[p] = (ushort)src[i];
    }
  }
}

__global__ __launch_bounds__(256, 2) void gemm_dual_kernel(
    const ushort* __restrict__ A, const ushort* __restrict__ Bs,
    const ushort* __restrict__ Bn, const float* __restrict__ bias,
    ushort* __restrict__ Sout, unsigned char* __restrict__ Yq, float* __restrict__ scales) {
  __shared__ ushort Al[2 * 4096];
  __shared__ ushort Bl[2 * 8192];
  __shared__ float red[256];
  gemm_dual_body<DIM_H>(blockIdx.x, Al, Bl, red, A, Bs, Bn, bias, Sout, Yq, scales);
}

// ---------------- gather: out = epilogue(S + mean(dequant(Yq[src]))) ----------------
template <bool FINAL>
__global__ __launch_bounds__(256) void gather_kernel(const unsigned char* __restrict__ Yq,
                                                     const float* __restrict__ scales,
                                                     const ushort* __restrict__ Sin,
                                                     const int* __restrict__ rowptr,
                                                     const int* __restrict__ deg,
                                                     const ushort* __restrict__ csr,
                                                     void* __restrict__ outv) {
  int node = blockIdx.x * 8 + (threadIdx.x >> 5);
  if (node >= N_NODES) return;
  int hl = threadIdx.x & 31;
  int start = rowptr[node];
  int d = deg[node];
  float acc[8];
#pragma unroll
  for (int i = 0; i < 8; ++i) acc[i] = 0.0f;
  float stot = 0.f;

  auto ub = [](uint u, int j) { return (float)((u >> (8 * j)) & 0xffu); };
  int e = 0;
  for (; e + 4 <= d; e += 4) {
    int s0 = csr[start + e], s1 = csr[start + e + 1];
    int s2 = csr[start + e + 2], s3 = csr[start + e + 3];
    float c0 = scales[s0], c1 = scales[s1], c2 = scales[s2], c3 = scales[s3];
    uint2 q0 = *reinterpret_cast<const uint2*>(Yq + (size_t)s0 * 256 + hl * 8);
    uint2 q1 = *reinterpret_cast<const uint2*>(Yq + (size_t)s1 * 256 + hl * 8);
    uint2 q2 = *reinterpret_cast<const uint2*>(Yq + (size_t)s2 * 256 + hl * 8);
    uint2 q3 = *reinterpret_cast<const uint2*>(Yq + (size_t)s3 * 256 + hl * 8);
    stot += c0 + c1 + c2 + c3;
#pragma unroll
    for (int j = 0; j < 4; ++j) {
      acc[j]     += c0 * ub(q0.x, j) + c1 * ub(q1.x, j) + c2 * ub(q2.x, j) + c3 * ub(q3.x, j);
      acc[4 + j] += c0 * ub(q0.y, j) + c1 * ub(q1.y, j) + c2 * ub(q2.y, j) + c3 * ub(q3.y, j);
    }
  }
  for (; e < d; ++e) {
    int s = csr[start + e];
    float c = scales[s];
    uint2 q = *reinterpret_cast<const uint2*>(Yq + (size_t)s * 256 + hl * 8);
    stot += c;
#pragma unroll
    for (int j = 0; j < 4; ++j) {
      acc[j]     += c * ub(q.x, j);
      acc[4 + j] += c * ub(q.y, j);
    }
  }

  float invd = 1.0f / fmaxf((float)d, 1.0f);
  float nb[8];
#pragma unroll
  for (int j = 0; j < 8; ++j) nb[j] = (acc[j] - 128.0f * stot) * invd;

  uint4 sv = *reinterpret_cast<const uint4*>(Sin + (size_t)node * 256 + hl * 8);
  uint su[4] = {sv.x, sv.y, sv.z, sv.w};

  if constexpr (FINAL) {
    float* out = (float*)outv + (size_t)node * 256 + (hl >> 4) * 128 + (hl & 15);
#pragma unroll
    for (int i = 0; i < 4; ++i) {
      out[(2 * i) * 16]     = nb[2 * i] + bf_lo(su[i]);
      out[(2 * i + 1) * 16] = nb[2 * i + 1] + bf_hi(su[i]);
    }
  } else {
    float v[8];
    float ssq = 0.f;
#pragma unroll
    for (int i = 0; i < 4; ++i) {
      float a = fmaxf(nb[2 * i] + bf_lo(su[i]), 0.0f);
      float b = fmaxf(nb[2 * i + 1] + bf_hi(su[i]), 0.0f);
      v[2 * i] = a; v[2 * i + 1] = b;
      ssq += a * a + b * b;
    }
    ssq += __shfl_xor(ssq, 1);
    ssq += __shfl_xor(ssq, 2);
    ssq += __shfl_xor(ssq, 4);
    ssq += __shfl_xor(ssq, 8);
    ssq += __shfl_xor(ssq, 16);
    float rn = 1.0f / fmaxf(sqrtf(ssq), 1e-12f);
    uint o[4];
#pragma unroll
    for (int i = 0; i < 4; ++i) {
      uint lo = f2bf(v[2 * i] * rn);
      uint hi = f2bf(v[2 * i + 1] * rn);
      o[i] = lo | (hi << 16);
    }
    *reinterpret_cast<uint4*>((ushort*)outv + (size_t)node * 256 + hl * 8) =
        make_uint4(o[0], o[1], o[2], o[3]);
  }
}

// ---------------- launch ----------------
extern "C" void kernel_launch(void* const* d_in, const int* in_sizes, int n_in,
                              void* d_out, int out_size, void* d_ws, size_t ws_size,
                              hipStream_t stream) {
  const float* x   = (const float*)d_in[0];
  const int*   src = (const int*)d_in[1];
  const int*   dst = (const int*)d_in[2];
  const float* Ws0 = (const float*)d_in[3];
  const float* Wn0 = (const float*)d_in[4];
  const float* b0  = (const float*)d_in[5];
  const float* Ws1 = (const float*)d_in[6];
  const float* Wn1 = (const float*)d_in[7];
  const float* b1  = (const float*)d_in[8];
  const float* Ws2 = (const float*)d_in[9];
  const float* Wn2 = (const float*)d_in[10];
  const float* b2  = (const float*)d_in[11];

  uintptr_t p = ((uintptr_t)d_ws + 255) & ~(uintptr_t)255;
  auto carve = [&](size_t bytes) {
    void* r = (void*)p;
    p += (bytes + 255) & ~(size_t)255;
    return r;
  };
  ushort* h0 = (ushort*)carve((size_t)N_NODES * DIM_IN * 2);
  ushort* h2 = h0;
  ushort* S_mid = (ushort*)carve((size_t)N_NODES * DIM_H * 2);
  ushort* h1 = (ushort*)carve((size_t)N_NODES * DIM_H * 2);
  unsigned char* Yq = (unsigned char*)carve((size_t)N_NODES * 256);
  float* scales = (float*)carve((size_t)N_NODES * 4);
  ushort* Ws0p = (ushort*)carve((size_t)DIM_IN * 256 * 2);
  ushort* Wn0p = (ushort*)carve((size_t)DIM_IN * 256 * 2);
  ushort* Ws1p = (ushort*)carve((size_t)DIM_H * 256 * 2);
  ushort* Wn1p = (ushort*)carve((size_t)DIM_H * 256 * 2);
  ushort* Ws2p = (ushort*)carve((size_t)DIM_H * 256 * 2);
  ushort* Wn2p = (ushort*)carve((size_t)DIM_H * 256 * 2);
  int* deg    = (int*)carve((size_t)N_NODES * 4);
  int* rowptr = (int*)carve((size_t)N_NODES * 4);
  int* cursor = (int*)carve((size_t)N_NODES * 4);
  int* stmp   = (int*)carve((size_t)N_NODES * 4);
  int* bsum   = (int*)carve(256 * 4);
  ushort* csr = (ushort*)carve((size_t)N_EDGES * 2);

  hipMemsetAsync(deg, 0, (size_t)N_NODES * 4, stream);

  // striped hist + log1p, with weight pack on the tail
  prep_kernel<<<STRIPE1_TOT + PACK_BLOCKS, 256, 0, stream>>>(
      x, h0, dst, deg, Ws0, Wn0, Ws1, Wn1, Ws2, Wn2,
      Ws0p, Wn0p, Ws1p, Wn1p, Ws2p, Wn2p);

  const int scanBlocks = (N_NODES + 255) / 256;
  scan1_kernel<<<scanBlocks, 256, 0, stream>>>(deg, stmp, bsum);
  scan2_kernel<<<1, 256, 0, stream>>>(bsum, scanBlocks);
  scan3_kernel<<<scanBlocks, 256, 0, stream>>>(stmp, bsum, rowptr, cursor);

  // striped layer-0 dual-GEMM + CSR fill (independent work, co-scheduled)
  gemm0_fill_kernel<<<GF_TOT, 256, 0, stream>>>(h0, Ws0p, Wn0p, b0, S_mid, Yq, scales,
                                                src, dst, cursor, csr);

  const int gatherBlocks = (N_NODES + 7) / 8;

  gather_kernel<false><<<gatherBlocks, 256, 0, stream>>>(Yq, scales, S_mid, rowptr, deg, csr, h1);
  gemm_dual_kernel<<<GEMM_BLOCKS, 256, 0, stream>>>(h1, Ws1p, Wn1p, b1, S_mid, Yq, scales);
  gather_kernel<false><<<gatherBlocks, 256, 0, stream>>>(Yq, scales, S_mid, rowptr, deg, csr, h2);
  gemm_dual_kernel<<<GEMM_BLOCKS, 256, 0, stream>>>(h2, Ws2p, Wn2p, b2, S_mid, Yq, scales);
  gather_kernel<true><<<gatherBlocks, 256, 0, stream>>>(Yq, scales, S_mid, rowptr, deg, csr, d_out);
}